// Round 1
// baseline (1825.595 us; speedup 1.0000x reference)
//
#include <hip/hip_runtime.h>
#include <math.h>

typedef __bf16 bf16_t;
typedef __bf16 bf16x8 __attribute__((ext_vector_type(8)));
typedef __bf16 bf16x4 __attribute__((ext_vector_type(4)));
typedef float  f32x4  __attribute__((ext_vector_type(4)));

static constexpr float ATT_SCALE = 0.15811388300841897f; // 40^-0.5

// ---- bf16 conversion helpers (bit-level, avoids reliance on __bf16 casts) ----
__device__ __forceinline__ bf16_t f2b(float f) {
  unsigned u = __float_as_uint(f);
  u = (u + 0x7fffu + ((u >> 16) & 1u)) >> 16;   // RNE
  unsigned short s = (unsigned short)u;
  bf16_t r;
  *(unsigned short*)&r = s;
  return r;
}
__device__ __forceinline__ float b2f(bf16_t b) {
  unsigned short s = *(const unsigned short*)&b;
  return __uint_as_float(((unsigned)s) << 16);
}
__device__ __forceinline__ void sto(float v, float* p)  { *p = v; }
__device__ __forceinline__ void sto(float v, bf16_t* p) { *p = f2b(v); }

// =========================== weight repack ===========================
// wqkv  f32 [320][960]  = [Wq1|Wk1|Wv1]
// wkv2  f32 [768][640]  = [Wk2|Wv2]
// wo2t  bf16 [320][320] = Wo2^T ; wff1t bf16 [2560][320] = Wff1^T ; wff2t bf16 [320][1280] = Wff2^T
__global__ __launch_bounds__(256) void prep_kernel(
    const float* __restrict__ Wq1, const float* __restrict__ Wk1, const float* __restrict__ Wv1,
    const float* __restrict__ Wk2, const float* __restrict__ Wv2, const float* __restrict__ Wo2,
    const float* __restrict__ Wff1, const float* __restrict__ Wff2,
    float* __restrict__ wqkv, float* __restrict__ wkv2,
    bf16_t* __restrict__ wo2t, bf16_t* __restrict__ wff1t, bf16_t* __restrict__ wff2t)
{
  const int T1 = 320*960;
  const int T2 = T1 + 768*640;
  const int T3 = T2 + 320*320;
  const int T4 = T3 + 2560*320;
  const int T5 = T4 + 320*1280;
  for (int i = blockIdx.x*256 + threadIdx.x; i < T5; i += gridDim.x*256) {
    if (i < T1) {
      int k = i / 960, n = i - k*960;
      float v = (n < 320) ? Wq1[k*320+n] : (n < 640) ? Wk1[k*320+n-320] : Wv1[k*320+n-640];
      wqkv[i] = v;
    } else if (i < T2) {
      int e = i - T1; int k = e / 640, n = e - k*640;
      wkv2[e] = (n < 320) ? Wk2[k*320+n] : Wv2[k*320+n-320];
    } else if (i < T3) {
      int e = i - T2; int n = e / 320, k = e - n*320;
      wo2t[e] = f2b(Wo2[k*320+n]);
    } else if (i < T4) {
      int e = i - T3; int n = e / 320, k = e - n*320;
      wff1t[e] = f2b(Wff1[(size_t)k*2560+n]);
    } else {
      int e = i - T4; int n = e / 1280, k = e - n*1280;
      wff2t[e] = f2b(Wff2[k*320+n]);
    }
  }
}

// =========================== LayerNorm (wave per row, 320 cols) ===========================
template<typename OT>
__global__ __launch_bounds__(256) void ln_kernel(
    const float* __restrict__ x, const float* __restrict__ g, const float* __restrict__ b,
    OT* __restrict__ out)
{
  const int lane = threadIdx.x & 63;
  const int row = blockIdx.x * 4 + (threadIdx.x >> 6);
  const float* xr = x + (size_t)row * 320;
  float v[5], s = 0.f, s2 = 0.f;
#pragma unroll
  for (int i = 0; i < 5; i++) { v[i] = xr[lane + i*64]; s += v[i]; s2 += v[i]*v[i]; }
#pragma unroll
  for (int o = 32; o; o >>= 1) { s += __shfl_xor(s, o); s2 += __shfl_xor(s2, o); }
  float mu = s * (1.f/320.f);
  float rs = rsqrtf(fmaxf(s2*(1.f/320.f) - mu*mu, 0.f) + 1e-5f);
#pragma unroll
  for (int i = 0; i < 5; i++) {
    int c = lane + i*64;
    sto((v[i]-mu)*rs*g[c] + b[c], &out[(size_t)row*320 + c]);
  }
}

// =========================== fp32 GEMM: C[M][N] = A[M][K] @ B[K][N] (+bias +resid) ===========================
// tile 128x64, BK=8, 256 threads, 8x4 microtile (rows ty*4 & 64+ty*4, cols tx*4)
__global__ __launch_bounds__(256) void gemm_f32(
    const float* __restrict__ A, const float* __restrict__ B,
    const float* __restrict__ bias, const float* __restrict__ resid,
    float* __restrict__ C, int M, int N, int K)
{
  __shared__ float As[8][128];   // [k][m] transposed
  __shared__ float Bs[8][64];    // [k][n]
  const int tid = threadIdx.x;
  const int m0 = blockIdx.x * 128, n0 = blockIdx.y * 64;
  const int tx = tid & 15, ty = tid >> 4;
  float acc[2][4][4] = {};
  for (int k0 = 0; k0 < K; k0 += 8) {
    __syncthreads();
    {
      int m = tid >> 1, kk = (tid & 1) * 4;
      int gm = m0 + m;
      float4 av = make_float4(0.f, 0.f, 0.f, 0.f);
      if (gm < M) av = *(const float4*)(A + (size_t)gm*K + k0 + kk);
      As[kk+0][m] = av.x; As[kk+1][m] = av.y; As[kk+2][m] = av.z; As[kk+3][m] = av.w;
    }
    if (tid < 128) {
      int kk = tid >> 4, nn = (tid & 15) * 4;
      *(float4*)&Bs[kk][nn] = *(const float4*)(B + (size_t)(k0+kk)*N + n0 + nn);
    }
    __syncthreads();
#pragma unroll
    for (int kk = 0; kk < 8; kk++) {
      float4 b4 = *(const float4*)&Bs[kk][tx*4];
      float4 a0 = *(const float4*)&As[kk][ty*4];
      float4 a1 = *(const float4*)&As[kk][64 + ty*4];
      float ar[2][4] = {{a0.x,a0.y,a0.z,a0.w},{a1.x,a1.y,a1.z,a1.w}};
      float br[4] = {b4.x,b4.y,b4.z,b4.w};
#pragma unroll
      for (int r = 0; r < 2; r++)
#pragma unroll
        for (int i = 0; i < 4; i++)
#pragma unroll
          for (int j = 0; j < 4; j++)
            acc[r][i][j] += ar[r][i] * br[j];
    }
  }
#pragma unroll
  for (int r = 0; r < 2; r++)
#pragma unroll
    for (int i = 0; i < 4; i++) {
      int gm = m0 + r*64 + ty*4 + i;
      if (gm >= M) continue;
#pragma unroll
      for (int j = 0; j < 4; j++) {
        int gn = n0 + tx*4 + j;
        float v = acc[r][i][j];
        if (bias)  v += bias[gn];
        if (resid) v += resid[(size_t)gm*N + gn];
        C[(size_t)gm*N + gn] = v;
      }
    }
}

// =========================== fp32 flash self-attention ===========================
// qkv [4096][960] (q|k|v each 320 = 8 heads x 40). grid (128, 8): 32 q-rows per block.
// thread = (qrow 0..31, key-slice 0..7); online softmax per thread; LDS merge of 8 partials.
__global__ __launch_bounds__(256) void attn_self_kernel(
    const float* __restrict__ qkv, float* __restrict__ Oa)
{
  __shared__ float sm[10752];           // staging (K 2560 + V 2560) / merge (256*42)
  float* Ks = sm;
  float* Vs = sm + 2560;
  const int tid = threadIdx.x;
  const int h = blockIdx.y;
  const int q0 = blockIdx.x * 32;
  const int qr = tid & 31, sl = tid >> 5;
  const float* qp = qkv + (size_t)(q0 + qr)*960 + h*40;
  float4 q[10];
#pragma unroll
  for (int i = 0; i < 10; i++) q[i] = *(const float4*)(qp + i*4);
  float o[40];
#pragma unroll
  for (int i = 0; i < 40; i++) o[i] = 0.f;
  float mx = -1e30f, l = 0.f;

  for (int k0 = 0; k0 < 4096; k0 += 64) {
    __syncthreads();
    for (int e = tid; e < 2560; e += 256) {
      int j = e / 40, d = e - j*40;
      const float* kp = qkv + (size_t)(k0+j)*960 + 320 + h*40 + d;
      Ks[e] = kp[0];
      Vs[e] = kp[320];
    }
    __syncthreads();
    float s[8];
#pragma unroll
    for (int jj = 0; jj < 8; jj++) {
      const float4* kr = (const float4*)(Ks + (sl*8+jj)*40);
      float a0=0.f, a1=0.f, a2=0.f, a3=0.f;
#pragma unroll
      for (int i = 0; i < 10; i++) {
        float4 kv = kr[i];
        a0 += q[i].x*kv.x; a1 += q[i].y*kv.y; a2 += q[i].z*kv.z; a3 += q[i].w*kv.w;
      }
      s[jj] = (a0+a1+a2+a3) * ATT_SCALE;
    }
    float tmax = s[0];
#pragma unroll
    for (int jj = 1; jj < 8; jj++) tmax = fmaxf(tmax, s[jj]);
    float mnew = fmaxf(mx, tmax);
    float corr = __expf(mx - mnew);
    mx = mnew;
    l *= corr;
#pragma unroll
    for (int i = 0; i < 40; i++) o[i] *= corr;
    float ps = 0.f;
#pragma unroll
    for (int jj = 0; jj < 8; jj++) { s[jj] = __expf(s[jj] - mnew); ps += s[jj]; }
    l += ps;
#pragma unroll
    for (int jj = 0; jj < 8; jj++) {
      const float4* vr = (const float4*)(Vs + (sl*8+jj)*40);
      float p = s[jj];
#pragma unroll
      for (int i = 0; i < 10; i++) {
        float4 vv = vr[i];
        o[i*4+0] += p*vv.x; o[i*4+1] += p*vv.y; o[i*4+2] += p*vv.z; o[i*4+3] += p*vv.w;
      }
    }
  }
  // merge 8 key-slice partials per q-row
  __syncthreads();
  float* mybuf = sm + tid*42;
  mybuf[0] = mx; mybuf[1] = l;
#pragma unroll
  for (int i = 0; i < 40; i++) mybuf[2+i] = o[i];
  __syncthreads();
  {
    const int qr2 = tid & 31, dg = tid >> 5;
    float M8[8], W8[8], gmx = -1e30f;
#pragma unroll
    for (int p = 0; p < 8; p++) { M8[p] = sm[(p*32+qr2)*42 + 0]; gmx = fmaxf(gmx, M8[p]); }
    float gl = 0.f;
#pragma unroll
    for (int p = 0; p < 8; p++) { W8[p] = __expf(M8[p]-gmx); gl += sm[(p*32+qr2)*42 + 1] * W8[p]; }
    float inv = 1.f / gl;
#pragma unroll
    for (int dd = 0; dd < 5; dd++) {
      int d = dg*5 + dd;
      float a = 0.f;
#pragma unroll
      for (int p = 0; p < 8; p++) a += sm[(p*32+qr2)*42 + 2 + d] * W8[p];
      Oa[(size_t)(q0+qr2)*320 + h*40 + d] = a * inv;
    }
  }
}

// =========================== cross-attention with focused-attention mask ===========================
// q2 f32 [4096][320]; kv2 f32 [77][640] (k|v); fam f32 [77][77]; out o2 bf16 [4096][320]
// grid (128, 8); 4 waves x 8 q-rows each; lane j handles keys {lane, lane+64}.
__global__ __launch_bounds__(256) void attn_cross_kernel(
    const float* __restrict__ q2, const float* __restrict__ kv2,
    const float* __restrict__ fam, const int* __restrict__ use_fca,
    bf16_t* __restrict__ o2)
{
  __shared__ float Kt[40*128];     // K^T [d][j], zero-padded j>=77
  __shared__ float Vsh[77*41];     // V [j][d]
  __shared__ float fams[77*81];    // fam [d][k], row stride 81
  __shared__ float simb[4*96];     // per-wave sim / p
  const int tid = threadIdx.x;
  const int h = blockIdx.y;
  const int q0 = blockIdx.x * 32;
  const int wid = tid >> 6, lane = tid & 63;

  for (int e = tid; e < 40*128; e += 256) Kt[e] = 0.f;
  __syncthreads();
  for (int e = tid; e < 77*40; e += 256) {
    int j = e / 40, d = e - j*40;
    Kt[d*128 + j] = kv2[(size_t)j*640 + h*40 + d];
    Vsh[j*41 + d] = kv2[(size_t)j*640 + 320 + h*40 + d];
  }
  for (int e = tid; e < 77*77; e += 256) {
    int d = e / 77;
    fams[e + d*4] = fam[e];        // d*81 + k
  }
  __syncthreads();

  const int fca = use_fca[0];
  const bool v1 = (64 + lane) < 77;
  float* sb = simb + wid*96;
  const float* fr0 = fams + lane*81;
  const float* fr1 = fams + (v1 ? (64+lane) : 76)*81;

  for (int it = 0; it < 8; it++) {
    int row = q0 + wid*8 + it;
    float qv = (lane < 40) ? q2[(size_t)row*320 + h*40 + lane] : 0.f;
    float s0 = 0.f, s1 = 0.f;
#pragma unroll
    for (int d = 0; d < 40; d++) {
      float qd = __shfl(qv, d);
      s0 += qd * Kt[d*128 + lane];
      s1 += qd * Kt[d*128 + 64 + lane];
    }
    s0 *= ATT_SCALE; s1 *= ATT_SCALE;
    if (fca) {
      sb[lane] = s0;
      if (v1) sb[64+lane] = s1;
      float fw0 = 0.f, fw1 = 0.f;
      for (int k = 0; k < 77; k++) {
        float sk = sb[k];
        fw0 += sk * fr0[k];
        fw1 += sk * fr1[k];
      }
      fw0 = fminf(fabsf(fw0), 1.f);
      fw1 = v1 ? fminf(fabsf(fw1), 1.f) : 0.f;
      float fm = fmaxf(fw0, fw1);
#pragma unroll
      for (int off = 32; off; off >>= 1) fm = fmaxf(fm, __shfl_xor(fm, off));
      float den = fm + 1e-6f;
      if (!(fw0/den > 0.6f)) s0 -= 50.f;
      if (v1 && !(fw1/den > 0.6f)) s1 -= 50.f;
    }
    if (!v1) s1 = -1e30f;
    float mxv = fmaxf(s0, s1);
#pragma unroll
    for (int off = 32; off; off >>= 1) mxv = fmaxf(mxv, __shfl_xor(mxv, off));
    float p0 = __expf(s0 - mxv);
    float p1 = v1 ? __expf(s1 - mxv) : 0.f;
    float ps = p0 + p1;
#pragma unroll
    for (int off = 32; off; off >>= 1) ps += __shfl_xor(ps, off);
    sb[lane] = p0;
    if (v1) sb[64+lane] = p1;
    if (lane < 40) {
      float a = 0.f;
      for (int j = 0; j < 77; j++) a += sb[j] * Vsh[j*41 + lane];
      sto(a / ps, &o2[(size_t)row*320 + h*40 + lane]);
    }
  }
}

// =========================== bf16 MFMA GEMM: C = A[M][K] @ Bt[N][K]^T ===========================
// tile 128x64, BK=64, 256 threads = 4 waves (2x2), wave tile 64x32 via 16x16x32 MFMA.
// A-frag: A[m=lane&15][k=quad*8+j]; B-frag from Bt row n: Bt[n=lane&15][k=quad*8+j];
// C/D: row=quad*4+reg, col=lane&15  (verified gfx950 layout).
template<int OUT_BF16>
__global__ __launch_bounds__(256) void gemm_bf16_kernel(
    const bf16_t* __restrict__ A, const bf16_t* __restrict__ Bt,
    const float* __restrict__ bias, const float* __restrict__ resid,
    void* __restrict__ Cout, int M, int N, int K)
{
  __shared__ bf16_t As[128][72];
  __shared__ bf16_t Bs[64][72];
  const int tid = threadIdx.x;
  const int m0 = blockIdx.x * 128, n0 = blockIdx.y * 64;
  const int w = tid >> 6, lane = tid & 63;
  const int wr = w >> 1, wc = w & 1;
  const int ln = lane & 15, qd = lane >> 4;
  f32x4 zero = {0.f, 0.f, 0.f, 0.f};
  f32x4 acc[4][2];
#pragma unroll
  for (int a = 0; a < 4; a++)
#pragma unroll
    for (int b = 0; b < 2; b++) acc[a][b] = zero;

  for (int k0 = 0; k0 < K; k0 += 64) {
    __syncthreads();
#pragma unroll
    for (int i = 0; i < 4; i++) {
      int vid = tid + i*256;
      int r = vid >> 3, c8 = (vid & 7) * 8;
      *(bf16x8*)&As[r][c8] = *(const bf16x8*)(A + (size_t)(m0+r)*K + k0 + c8);
    }
#pragma unroll
    for (int i = 0; i < 2; i++) {
      int vid = tid + i*256;
      int r = vid >> 3, c8 = (vid & 7) * 8;
      *(bf16x8*)&Bs[r][c8] = *(const bf16x8*)(Bt + (size_t)(n0+r)*K + k0 + c8);
    }
    __syncthreads();
#pragma unroll
    for (int c = 0; c < 2; c++) {
      bf16x8 af[4], bfr[2];
#pragma unroll
      for (int mt = 0; mt < 4; mt++)
        af[mt] = *(const bf16x8*)&As[wr*64 + mt*16 + ln][c*32 + qd*8];
#pragma unroll
      for (int nt = 0; nt < 2; nt++)
        bfr[nt] = *(const bf16x8*)&Bs[wc*32 + nt*16 + ln][c*32 + qd*8];
#pragma unroll
      for (int mt = 0; mt < 4; mt++)
#pragma unroll
        for (int nt = 0; nt < 2; nt++)
          acc[mt][nt] = __builtin_amdgcn_mfma_f32_16x16x32_bf16(af[mt], bfr[nt], acc[mt][nt], 0, 0, 0);
    }
  }
#pragma unroll
  for (int mt = 0; mt < 4; mt++)
#pragma unroll
    for (int nt = 0; nt < 2; nt++)
#pragma unroll
      for (int r = 0; r < 4; r++) {
        int gm = m0 + wr*64 + mt*16 + qd*4 + r;
        int gn = n0 + wc*32 + nt*16 + ln;
        float v = acc[mt][nt][r];
        if (bias)  v += bias[gn];
        if (resid) v += resid[(size_t)gm*N + gn];
        if (OUT_BF16) sto(v, &((bf16_t*)Cout)[(size_t)gm*N + gn]);
        else          sto(v, &((float*)Cout)[(size_t)gm*N + gn]);
      }
}

// =========================== GEGLU: gg = a * gelu_exact(gate) ===========================
__global__ __launch_bounds__(256) void geglu_kernel(
    const bf16_t* __restrict__ proj, bf16_t* __restrict__ gg)
{
  int idx = blockIdx.x * 256 + threadIdx.x;      // 0 .. 4096*320-1 (x4 cols)
  int m = idx / 320, c4 = (idx - m*320) * 4;
  bf16x4 a = *(const bf16x4*)(proj + (size_t)m*2560 + c4);
  bf16x4 g = *(const bf16x4*)(proj + (size_t)m*2560 + 1280 + c4);
  bf16x4 r;
#pragma unroll
  for (int i = 0; i < 4; i++) {
    float gf = b2f(g[i]);
    float ge = 0.5f * gf * (1.f + erff(gf * 0.70710678118654752f));
    r[i] = f2b(b2f(a[i]) * ge);
  }
  *(bf16x4*)(gg + (size_t)m*1280 + c4) = r;
}

// =========================== launch ===========================
extern "C" void kernel_launch(void* const* d_in, const int* in_sizes, int n_in,
                              void* d_out, int out_size, void* d_ws, size_t ws_size,
                              hipStream_t stream)
{
  const float* x    = (const float*)d_in[0];
  const float* ctx  = (const float*)d_in[1];
  const float* fam  = (const float*)d_in[2];
  const float* g1   = (const float*)d_in[3];
  const float* b1   = (const float*)d_in[4];
  const float* g2   = (const float*)d_in[5];
  const float* b2   = (const float*)d_in[6];
  const float* g3   = (const float*)d_in[7];
  const float* b3   = (const float*)d_in[8];
  const float* Wq1  = (const float*)d_in[9];
  const float* Wk1  = (const float*)d_in[10];
  const float* Wv1  = (const float*)d_in[11];
  const float* Wo1  = (const float*)d_in[12];
  const float* bo1  = (const float*)d_in[13];
  const float* Wq2  = (const float*)d_in[14];
  const float* Wk2  = (const float*)d_in[15];
  const float* Wv2  = (const float*)d_in[16];
  const float* Wo2  = (const float*)d_in[17];
  const float* bo2  = (const float*)d_in[18];
  const float* Wff1 = (const float*)d_in[19];
  const float* bff1 = (const float*)d_in[20];
  const float* Wff2 = (const float*)d_in[21];
  const float* bff2 = (const float*)d_in[22];
  const int*   ufca = (const int*)d_in[23];

  char* ws = (char*)d_ws;
  // region plan (bytes); proj overlaps [qkv1+o1a], gg overlaps [x2+q2] (lifetimes disjoint)
  float*  qkv1 = (float*)(ws + 0);          // 15,728,640  f32 [4096][960]
  float*  o1a  = (float*)(ws + 15728640);   //  5,242,880  f32 [4096][320]
  float*  hbuf = (float*)(ws + 20971520);   //  5,242,880  f32 [4096][320]
  float*  x2   = (float*)(ws + 26214400);   //  5,242,880  f32 [4096][320]
  float*  q2   = (float*)(ws + 31457280);   //  5,242,880  f32 [4096][320]
  float*  kv2  = (float*)(ws + 36700160);   //    197,120  f32 [77][640]
  bf16_t* o2   = (bf16_t*)(ws + 36897280);  //  2,621,440  bf16 [4096][320]
  float*  x3   = (float*)(ws + 39518720);   //  5,242,880  f32 [4096][320]
  bf16_t* h3b  = (bf16_t*)(ws + 44761600);  //  2,621,440  bf16 [4096][320]
  bf16_t* proj = (bf16_t*)(ws + 0);         // 20,971,520  bf16 [4096][2560] (overlap)
  bf16_t* gg   = (bf16_t*)(ws + 26214400);  // 10,485,760  bf16 [4096][1280] (overlap)
  float*  wqkv = (float*)(ws + 47383040);   //  1,228,800
  float*  wkv2 = (float*)(ws + 48611840);   //  1,966,080
  bf16_t* wo2t  = (bf16_t*)(ws + 50577920); //    204,800
  bf16_t* wff1t = (bf16_t*)(ws + 50782720); //  1,638,400
  bf16_t* wff2t = (bf16_t*)(ws + 52421120); //    819,200  -> total 53,240,320

  float* xout = (float*)d_out;

  prep_kernel<<<1024, 256, 0, stream>>>(Wq1, Wk1, Wv1, Wk2, Wv2, Wo2, Wff1, Wff2,
                                        wqkv, wkv2, wo2t, wff1t, wff2t);
  // --- attn1 (all fp32 upstream of fca threshold) ---
  ln_kernel<float><<<1024, 256, 0, stream>>>(x, g1, b1, hbuf);
  gemm_f32<<<dim3(32,15), 256, 0, stream>>>(hbuf, wqkv, nullptr, nullptr, qkv1, 4096, 960, 320);
  attn_self_kernel<<<dim3(128,8), 256, 0, stream>>>(qkv1, o1a);
  gemm_f32<<<dim3(32,5), 256, 0, stream>>>(o1a, Wo1, bo1, x, x2, 4096, 320, 320);
  // --- attn2 ---
  ln_kernel<float><<<1024, 256, 0, stream>>>(x2, g2, b2, hbuf);
  gemm_f32<<<dim3(32,5), 256, 0, stream>>>(hbuf, Wq2, nullptr, nullptr, q2, 4096, 320, 320);
  gemm_f32<<<dim3(1,10), 256, 0, stream>>>(ctx, wkv2, nullptr, nullptr, kv2, 77, 640, 768);
  attn_cross_kernel<<<dim3(128,8), 256, 0, stream>>>(q2, kv2, fam, ufca, o2);
  gemm_bf16_kernel<0><<<dim3(32,5), 256, 0, stream>>>(o2, wo2t, bo2, x2, x3, 4096, 320, 320);
  // --- GEGLU FF (bf16 MFMA, downstream-safe) ---
  ln_kernel<bf16_t><<<1024, 256, 0, stream>>>(x3, g3, b3, h3b);
  gemm_bf16_kernel<1><<<dim3(32,40), 256, 0, stream>>>(h3b, wff1t, bff1, nullptr, proj, 4096, 2560, 320);
  geglu_kernel<<<5120, 256, 0, stream>>>(proj, gg);
  gemm_bf16_kernel<0><<<dim3(32,5), 256, 0, stream>>>(gg, wff2t, bff2, x3, xout, 4096, 320, 1280);
}

// Round 2
// 591.061 us; speedup vs baseline: 3.0887x; 3.0887x over previous
//
#include <hip/hip_runtime.h>
#include <math.h>

typedef __bf16 bf16_t;
typedef __bf16 bf16x8 __attribute__((ext_vector_type(8)));
typedef __bf16 bf16x4 __attribute__((ext_vector_type(4)));
typedef float  f32x4  __attribute__((ext_vector_type(4)));

static constexpr float ATT_SCALE = 0.15811388300841897f; // 40^-0.5

__device__ __forceinline__ bf16_t f2b(float f) {
  unsigned u = __float_as_uint(f);
  u = (u + 0x7fffu + ((u >> 16) & 1u)) >> 16;   // RNE
  unsigned short s = (unsigned short)u;
  bf16_t r;
  *(unsigned short*)&r = s;
  return r;
}
__device__ __forceinline__ float b2f(bf16_t b) {
  unsigned short s = *(const unsigned short*)&b;
  return __uint_as_float(((unsigned)s) << 16);
}
__device__ __forceinline__ void sto(float v, float* p)  { *p = v; }
__device__ __forceinline__ void sto(float v, bf16_t* p) { *p = f2b(v); }

// =========================== weight repack ===========================
// wqkvt bf16 [960][320] = [Wq1|Wk1|Wv1]^T ; wo1t bf16 [320][320] = Wo1^T
// wkv2  f32 [768][640]  = [Wk2|Wv2]
// wo2t bf16 [320][320] = Wo2^T ; wff1t bf16 [2560][320] = Wff1^T ; wff2t bf16 [320][1280] = Wff2^T
__global__ __launch_bounds__(256) void prep_kernel(
    const float* __restrict__ Wq1, const float* __restrict__ Wk1, const float* __restrict__ Wv1,
    const float* __restrict__ Wo1,
    const float* __restrict__ Wk2, const float* __restrict__ Wv2, const float* __restrict__ Wo2,
    const float* __restrict__ Wff1, const float* __restrict__ Wff2,
    bf16_t* __restrict__ wqkvt, bf16_t* __restrict__ wo1t, float* __restrict__ wkv2,
    bf16_t* __restrict__ wo2t, bf16_t* __restrict__ wff1t, bf16_t* __restrict__ wff2t)
{
  const int T1 = 960*320;
  const int T2 = T1 + 320*320;
  const int T3 = T2 + 768*640;
  const int T4 = T3 + 320*320;
  const int T5 = T4 + 2560*320;
  const int T6 = T5 + 320*1280;
  for (int i = blockIdx.x*256 + threadIdx.x; i < T6; i += gridDim.x*256) {
    if (i < T1) {
      int n = i / 320, k = i - n*320;
      float v = (n < 320) ? Wq1[k*320+n] : (n < 640) ? Wk1[k*320+n-320] : Wv1[k*320+n-640];
      wqkvt[i] = f2b(v);
    } else if (i < T2) {
      int e = i - T1; int n = e / 320, k = e - n*320;
      wo1t[e] = f2b(Wo1[k*320+n]);
    } else if (i < T3) {
      int e = i - T2; int k = e / 640, n = e - k*640;
      wkv2[e] = (n < 320) ? Wk2[k*320+n] : Wv2[k*320+n-320];
    } else if (i < T4) {
      int e = i - T3; int n = e / 320, k = e - n*320;
      wo2t[e] = f2b(Wo2[k*320+n]);
    } else if (i < T5) {
      int e = i - T4; int n = e / 320, k = e - n*320;
      wff1t[e] = f2b(Wff1[(size_t)k*2560+n]);
    } else {
      int e = i - T5; int n = e / 1280, k = e - n*1280;
      wff2t[e] = f2b(Wff2[k*320+n]);
    }
  }
}

// =========================== LayerNorm (wave per row, 320 cols) ===========================
template<typename OT>
__global__ __launch_bounds__(256) void ln_kernel(
    const float* __restrict__ x, const float* __restrict__ g, const float* __restrict__ b,
    OT* __restrict__ out)
{
  const int lane = threadIdx.x & 63;
  const int row = blockIdx.x * 4 + (threadIdx.x >> 6);
  const float* xr = x + (size_t)row * 320;
  float v[5], s = 0.f, s2 = 0.f;
#pragma unroll
  for (int i = 0; i < 5; i++) { v[i] = xr[lane + i*64]; s += v[i]; s2 += v[i]*v[i]; }
#pragma unroll
  for (int o = 32; o; o >>= 1) { s += __shfl_xor(s, o); s2 += __shfl_xor(s2, o); }
  float mu = s * (1.f/320.f);
  float rs = rsqrtf(fmaxf(s2*(1.f/320.f) - mu*mu, 0.f) + 1e-5f);
#pragma unroll
  for (int i = 0; i < 5; i++) {
    int c = lane + i*64;
    sto((v[i]-mu)*rs*g[c] + b[c], &out[(size_t)row*320 + c]);
  }
}

// =========================== fp32 GEMM: C[M][N] = A[M][K] @ B[K][N] ===========================
__global__ __launch_bounds__(256) void gemm_f32(
    const float* __restrict__ A, const float* __restrict__ B,
    const float* __restrict__ bias, const float* __restrict__ resid,
    float* __restrict__ C, int M, int N, int K)
{
  __shared__ float As[8][128];
  __shared__ float Bs[8][64];
  const int tid = threadIdx.x;
  const int m0 = blockIdx.x * 128, n0 = blockIdx.y * 64;
  const int tx = tid & 15, ty = tid >> 4;
  float acc[2][4][4] = {};
  for (int k0 = 0; k0 < K; k0 += 8) {
    __syncthreads();
    {
      int m = tid >> 1, kk = (tid & 1) * 4;
      int gm = m0 + m;
      float4 av = make_float4(0.f, 0.f, 0.f, 0.f);
      if (gm < M) av = *(const float4*)(A + (size_t)gm*K + k0 + kk);
      As[kk+0][m] = av.x; As[kk+1][m] = av.y; As[kk+2][m] = av.z; As[kk+3][m] = av.w;
    }
    if (tid < 128) {
      int kk = tid >> 4, nn = (tid & 15) * 4;
      *(float4*)&Bs[kk][nn] = *(const float4*)(B + (size_t)(k0+kk)*N + n0 + nn);
    }
    __syncthreads();
#pragma unroll
    for (int kk = 0; kk < 8; kk++) {
      float4 b4 = *(const float4*)&Bs[kk][tx*4];
      float4 a0 = *(const float4*)&As[kk][ty*4];
      float4 a1 = *(const float4*)&As[kk][64 + ty*4];
      float ar[2][4] = {{a0.x,a0.y,a0.z,a0.w},{a1.x,a1.y,a1.z,a1.w}};
      float br[4] = {b4.x,b4.y,b4.z,b4.w};
#pragma unroll
      for (int r = 0; r < 2; r++)
#pragma unroll
        for (int i = 0; i < 4; i++)
#pragma unroll
          for (int j = 0; j < 4; j++)
            acc[r][i][j] += ar[r][i] * br[j];
    }
  }
#pragma unroll
  for (int r = 0; r < 2; r++)
#pragma unroll
    for (int i = 0; i < 4; i++) {
      int gm = m0 + r*64 + ty*4 + i;
      if (gm >= M) continue;
#pragma unroll
      for (int j = 0; j < 4; j++) {
        int gn = n0 + tx*4 + j;
        float v = acc[r][i][j];
        if (bias)  v += bias[gn];
        if (resid) v += resid[(size_t)gm*N + gn];
        C[(size_t)gm*N + gn] = v;
      }
    }
}

// =========================== V^T repack: qkvb [4096][960] -> vtg [8][40][4096] ===========================
__global__ __launch_bounds__(256) void repack_vt_kernel(
    const bf16_t* __restrict__ qkvb, bf16_t* __restrict__ vtg)
{
  __shared__ bf16_t T[64*44];
  const int tid = threadIdx.x;
  const int t0 = blockIdx.x * 64, h = blockIdx.y;
  for (int e = tid; e < 320; e += 256) {
    int t = e / 5, c8 = (e - t*5) * 8;
    *(bf16x8*)&T[t*44 + c8] = *(const bf16x8*)(qkvb + (size_t)(t0+t)*960 + 640 + h*40 + c8);
  }
  __syncthreads();
  for (int e = tid; e < 320; e += 256) {
    int d = e >> 3, t8 = (e & 7) * 8;
    bf16x8 v;
#pragma unroll
    for (int j = 0; j < 8; j++) v[j] = T[(t8+j)*44 + d];
    *(bf16x8*)&vtg[((size_t)h*40 + d)*4096 + t0 + t8] = v;
  }
}

// =========================== bf16 MFMA flash self-attention ===========================
// qkvb [4096][960] (q|k|v, 8 heads x 40). vtg [8][40][4096] = V^T per head.
// block: 64 q-rows x 1 head; 4 waves x 16 q-rows; K-tile 64. grid (64, 8).
__global__ __launch_bounds__(256) void flash_self_kernel(
    const bf16_t* __restrict__ qkvb, const bf16_t* __restrict__ vtg,
    bf16_t* __restrict__ o1a)
{
  __shared__ bf16_t Ks[64*72];      // [key][d], d 40..63 zero
  __shared__ bf16_t Vts[48*72];     // [col][key], col 40..47 zero
  __shared__ bf16_t Pds[4*16*72];   // per-wave P round-trip
  const int tid = threadIdx.x;
  const int w = tid >> 6, lane = tid & 63;
  const int ln = lane & 15, qd = lane >> 4;
  const int h = blockIdx.y;
  const int q0 = blockIdx.x * 64;
  const int qrow = q0 + w*16 + ln;

  // loop-invariant Q fragments (A-layout: A[m=ln][k=qd*8+j]); d>=40 must be zero
  bf16x8 aq0 = *(const bf16x8*)(qkvb + (size_t)qrow*960 + h*40 + qd*8);   // d 0..31
  bf16x8 aq1 = {};
  if (qd == 0) aq1 = *(const bf16x8*)(qkvb + (size_t)qrow*960 + h*40 + 32); // d 32..39

  // zero Vts rows 40..47 (keys 0..63)
  if (tid < 64) {
    bf16x8 z = {};
    int d = 40 + (tid >> 3), k8 = (tid & 7) * 8;
    *(bf16x8*)&Vts[d*72 + k8] = z;
  }

  f32x4 zero4 = {0.f, 0.f, 0.f, 0.f};
  f32x4 oacc[3];
  oacc[0] = zero4; oacc[1] = zero4; oacc[2] = zero4;
  float m_[4] = {-1e30f, -1e30f, -1e30f, -1e30f};
  float l_[4] = {0.f, 0.f, 0.f, 0.f};
  bf16_t* Pw = Pds + w*16*72;

  for (int k0 = 0; k0 < 4096; k0 += 64) {
    __syncthreads();
    // stage K tile: 64 keys x 64 d (d>=40 zero)
#pragma unroll
    for (int i = 0; i < 2; i++) {
      int e = tid + i*256;
      int row = e >> 3, c = e & 7;
      bf16x8 kv = {};
      if (c < 5) kv = *(const bf16x8*)(qkvb + (size_t)(k0+row)*960 + 320 + h*40 + c*8);
      *(bf16x8*)&Ks[row*72 + c*8] = kv;
    }
    // stage V^T tile: 40 d-rows x 64 keys
    {
      int d = tid >> 3, k8 = (tid & 7) * 8;
      *(bf16x8*)&Vts[d*72 + k8] = *(const bf16x8*)(vtg + ((size_t)h*40 + d)*4096 + k0 + k8);
      if (tid < 64) {
        int d2 = 32 + (tid >> 3);
        *(bf16x8*)&Vts[d2*72 + k8] = *(const bf16x8*)(vtg + ((size_t)h*40 + d2)*4096 + k0 + k8);
      }
    }
    __syncthreads();

    // S = Q K^T  (4 n-tiles of 16 keys, 2 k-steps)
    f32x4 sacc[4];
#pragma unroll
    for (int nt = 0; nt < 4; nt++) {
      bf16x8 b0 = *(const bf16x8*)&Ks[(nt*16+ln)*72 + qd*8];
      bf16x8 b1 = *(const bf16x8*)&Ks[(nt*16+ln)*72 + 32 + qd*8];
      f32x4 s = __builtin_amdgcn_mfma_f32_16x16x32_bf16(aq0, b0, zero4, 0, 0, 0);
      sacc[nt]  = __builtin_amdgcn_mfma_f32_16x16x32_bf16(aq1, b1, s, 0, 0, 0);
    }
    // scale
#pragma unroll
    for (int nt = 0; nt < 4; nt++)
#pragma unroll
      for (int r = 0; r < 4; r++) sacc[nt][r] *= ATT_SCALE;

    // online softmax (rows qd*4+r; key-reduce across 4 n-tiles + 16 lanes of quad-group)
    float alpha[4];
#pragma unroll
    for (int r = 0; r < 4; r++) {
      float mr = fmaxf(fmaxf(sacc[0][r], sacc[1][r]), fmaxf(sacc[2][r], sacc[3][r]));
#pragma unroll
      for (int o = 8; o; o >>= 1) mr = fmaxf(mr, __shfl_xor(mr, o));
      float mnew = fmaxf(m_[r], mr);
      alpha[r] = __expf(m_[r] - mnew);
      m_[r] = mnew;
    }
    float psum[4] = {0.f, 0.f, 0.f, 0.f};
#pragma unroll
    for (int nt = 0; nt < 4; nt++)
#pragma unroll
      for (int r = 0; r < 4; r++) {
        float pv = __expf(sacc[nt][r] - m_[r]);
        psum[r] += pv;
        Pw[(qd*4+r)*72 + nt*16 + ln] = f2b(pv);
      }
#pragma unroll
    for (int r = 0; r < 4; r++) {
#pragma unroll
      for (int o = 8; o; o >>= 1) psum[r] += __shfl_xor(psum[r], o);
      l_[r] = l_[r]*alpha[r] + psum[r];
    }
#pragma unroll
    for (int nt = 0; nt < 3; nt++)
#pragma unroll
      for (int r = 0; r < 4; r++) oacc[nt][r] *= alpha[r];

    // O += P V  (P from wave-private LDS: DS ops are in-order per wave)
    bf16x8 pa0 = *(const bf16x8*)&Pw[ln*72 + qd*8];
    bf16x8 pa1 = *(const bf16x8*)&Pw[ln*72 + 32 + qd*8];
#pragma unroll
    for (int nt = 0; nt < 3; nt++) {
      bf16x8 vb0 = *(const bf16x8*)&Vts[(nt*16+ln)*72 + qd*8];
      bf16x8 vb1 = *(const bf16x8*)&Vts[(nt*16+ln)*72 + 32 + qd*8];
      oacc[nt] = __builtin_amdgcn_mfma_f32_16x16x32_bf16(pa0, vb0, oacc[nt], 0, 0, 0);
      oacc[nt] = __builtin_amdgcn_mfma_f32_16x16x32_bf16(pa1, vb1, oacc[nt], 0, 0, 0);
    }
  }

  float inv[4];
#pragma unroll
  for (int r = 0; r < 4; r++) inv[r] = 1.f / l_[r];
#pragma unroll
  for (int nt = 0; nt < 3; nt++)
#pragma unroll
    for (int r = 0; r < 4; r++) {
      int col = nt*16 + ln;
      if (col < 40)
        o1a[(size_t)(q0 + w*16 + qd*4 + r)*320 + h*40 + col] = f2b(oacc[nt][r]*inv[r]);
    }
}

// =========================== cross-attention with focused-attention mask ===========================
__global__ __launch_bounds__(256) void attn_cross_kernel(
    const float* __restrict__ q2, const float* __restrict__ kv2,
    const float* __restrict__ fam, const int* __restrict__ use_fca,
    bf16_t* __restrict__ o2)
{
  __shared__ float Kt[40*128];
  __shared__ float Vsh[77*41];
  __shared__ float fams[77*81];
  __shared__ float simb[4*96];
  const int tid = threadIdx.x;
  const int h = blockIdx.y;
  const int q0 = blockIdx.x * 32;
  const int wid = tid >> 6, lane = tid & 63;

  for (int e = tid; e < 40*128; e += 256) Kt[e] = 0.f;
  __syncthreads();
  for (int e = tid; e < 77*40; e += 256) {
    int j = e / 40, d = e - j*40;
    Kt[d*128 + j] = kv2[(size_t)j*640 + h*40 + d];
    Vsh[j*41 + d] = kv2[(size_t)j*640 + 320 + h*40 + d];
  }
  for (int e = tid; e < 77*77; e += 256) {
    int d = e / 77;
    fams[e + d*4] = fam[e];
  }
  __syncthreads();

  const int fca = use_fca[0];
  const bool v1 = (64 + lane) < 77;
  float* sb = simb + wid*96;
  const float* fr0 = fams + lane*81;
  const float* fr1 = fams + (v1 ? (64+lane) : 76)*81;

  for (int it = 0; it < 8; it++) {
    int row = q0 + wid*8 + it;
    float qv = (lane < 40) ? q2[(size_t)row*320 + h*40 + lane] : 0.f;
    float s0 = 0.f, s1 = 0.f;
#pragma unroll
    for (int d = 0; d < 40; d++) {
      float qd = __shfl(qv, d);
      s0 += qd * Kt[d*128 + lane];
      s1 += qd * Kt[d*128 + 64 + lane];
    }
    s0 *= ATT_SCALE; s1 *= ATT_SCALE;
    if (fca) {
      sb[lane] = s0;
      if (v1) sb[64+lane] = s1;
      float fw0 = 0.f, fw1 = 0.f;
      for (int k = 0; k < 77; k++) {
        float sk = sb[k];
        fw0 += sk * fr0[k];
        fw1 += sk * fr1[k];
      }
      fw0 = fminf(fabsf(fw0), 1.f);
      fw1 = v1 ? fminf(fabsf(fw1), 1.f) : 0.f;
      float fm = fmaxf(fw0, fw1);
#pragma unroll
      for (int off = 32; off; off >>= 1) fm = fmaxf(fm, __shfl_xor(fm, off));
      float den = fm + 1e-6f;
      if (!(fw0/den > 0.6f)) s0 -= 50.f;
      if (v1 && !(fw1/den > 0.6f)) s1 -= 50.f;
    }
    if (!v1) s1 = -1e30f;
    float mxv = fmaxf(s0, s1);
#pragma unroll
    for (int off = 32; off; off >>= 1) mxv = fmaxf(mxv, __shfl_xor(mxv, off));
    float p0 = __expf(s0 - mxv);
    float p1 = v1 ? __expf(s1 - mxv) : 0.f;
    float ps = p0 + p1;
#pragma unroll
    for (int off = 32; off; off >>= 1) ps += __shfl_xor(ps, off);
    sb[lane] = p0;
    if (v1) sb[64+lane] = p1;
    if (lane < 40) {
      float a = 0.f;
      for (int j = 0; j < 77; j++) a += sb[j] * Vsh[j*41 + lane];
      sto(a / ps, &o2[(size_t)row*320 + h*40 + lane]);
    }
  }
}

// =========================== bf16 MFMA GEMM: C = A[M][K] @ Bt[N][K]^T ===========================
template<int OUT_BF16>
__global__ __launch_bounds__(256) void gemm_bf16_kernel(
    const bf16_t* __restrict__ A, const bf16_t* __restrict__ Bt,
    const float* __restrict__ bias, const float* __restrict__ resid,
    void* __restrict__ Cout, int M, int N, int K)
{
  __shared__ bf16_t As[128][72];
  __shared__ bf16_t Bs[64][72];
  const int tid = threadIdx.x;
  const int m0 = blockIdx.x * 128, n0 = blockIdx.y * 64;
  const int w = tid >> 6, lane = tid & 63;
  const int wr = w >> 1, wc = w & 1;
  const int ln = lane & 15, qd = lane >> 4;
  f32x4 zero = {0.f, 0.f, 0.f, 0.f};
  f32x4 acc[4][2];
#pragma unroll
  for (int a = 0; a < 4; a++)
#pragma unroll
    for (int b = 0; b < 2; b++) acc[a][b] = zero;

  for (int k0 = 0; k0 < K; k0 += 64) {
    __syncthreads();
#pragma unroll
    for (int i = 0; i < 4; i++) {
      int vid = tid + i*256;
      int r = vid >> 3, c8 = (vid & 7) * 8;
      *(bf16x8*)&As[r][c8] = *(const bf16x8*)(A + (size_t)(m0+r)*K + k0 + c8);
    }
#pragma unroll
    for (int i = 0; i < 2; i++) {
      int vid = tid + i*256;
      int r = vid >> 3, c8 = (vid & 7) * 8;
      *(bf16x8*)&Bs[r][c8] = *(const bf16x8*)(Bt + (size_t)(n0+r)*K + k0 + c8);
    }
    __syncthreads();
#pragma unroll
    for (int c = 0; c < 2; c++) {
      bf16x8 af[4], bfr[2];
#pragma unroll
      for (int mt = 0; mt < 4; mt++)
        af[mt] = *(const bf16x8*)&As[wr*64 + mt*16 + ln][c*32 + qd*8];
#pragma unroll
      for (int nt = 0; nt < 2; nt++)
        bfr[nt] = *(const bf16x8*)&Bs[wc*32 + nt*16 + ln][c*32 + qd*8];
#pragma unroll
      for (int mt = 0; mt < 4; mt++)
#pragma unroll
        for (int nt = 0; nt < 2; nt++)
          acc[mt][nt] = __builtin_amdgcn_mfma_f32_16x16x32_bf16(af[mt], bfr[nt], acc[mt][nt], 0, 0, 0);
    }
  }
#pragma unroll
  for (int mt = 0; mt < 4; mt++)
#pragma unroll
    for (int nt = 0; nt < 2; nt++)
#pragma unroll
      for (int r = 0; r < 4; r++) {
        int gm = m0 + wr*64 + mt*16 + qd*4 + r;
        int gn = n0 + wc*32 + nt*16 + ln;
        float v = acc[mt][nt][r];
        if (bias)  v += bias[gn];
        if (resid) v += resid[(size_t)gm*N + gn];
        if (OUT_BF16) sto(v, &((bf16_t*)Cout)[(size_t)gm*N + gn]);
        else          sto(v, &((float*)Cout)[(size_t)gm*N + gn]);
      }
}

// =========================== GEGLU ===========================
__global__ __launch_bounds__(256) void geglu_kernel(
    const bf16_t* __restrict__ proj, bf16_t* __restrict__ gg)
{
  int idx = blockIdx.x * 256 + threadIdx.x;
  int m = idx / 320, c4 = (idx - m*320) * 4;
  bf16x4 a = *(const bf16x4*)(proj + (size_t)m*2560 + c4);
  bf16x4 g = *(const bf16x4*)(proj + (size_t)m*2560 + 1280 + c4);
  bf16x4 r;
#pragma unroll
  for (int i = 0; i < 4; i++) {
    float gf = b2f(g[i]);
    float ge = 0.5f * gf * (1.f + erff(gf * 0.70710678118654752f));
    r[i] = f2b(b2f(a[i]) * ge);
  }
  *(bf16x4*)(gg + (size_t)m*1280 + c4) = r;
}

// =========================== launch ===========================
extern "C" void kernel_launch(void* const* d_in, const int* in_sizes, int n_in,
                              void* d_out, int out_size, void* d_ws, size_t ws_size,
                              hipStream_t stream)
{
  const float* x    = (const float*)d_in[0];
  const float* ctx  = (const float*)d_in[1];
  const float* fam  = (const float*)d_in[2];
  const float* g1   = (const float*)d_in[3];
  const float* b1   = (const float*)d_in[4];
  const float* g2   = (const float*)d_in[5];
  const float* b2   = (const float*)d_in[6];
  const float* g3   = (const float*)d_in[7];
  const float* b3   = (const float*)d_in[8];
  const float* Wq1  = (const float*)d_in[9];
  const float* Wk1  = (const float*)d_in[10];
  const float* Wv1  = (const float*)d_in[11];
  const float* Wo1  = (const float*)d_in[12];
  const float* bo1  = (const float*)d_in[13];
  const float* Wq2  = (const float*)d_in[14];
  const float* Wk2  = (const float*)d_in[15];
  const float* Wv2  = (const float*)d_in[16];
  const float* Wo2  = (const float*)d_in[17];
  const float* bo2  = (const float*)d_in[18];
  const float* Wff1 = (const float*)d_in[19];
  const float* bff1 = (const float*)d_in[20];
  const float* Wff2 = (const float*)d_in[21];
  const float* bff2 = (const float*)d_in[22];
  const int*   ufca = (const int*)d_in[23];

  char* ws = (char*)d_ws;
  bf16_t* qkvb = (bf16_t*)(ws + 0);          //  7,864,320  bf16 [4096][960]
  bf16_t* vtg  = (bf16_t*)(ws + 7864320);    //  2,621,440  bf16 [8][40][4096]
  bf16_t* o1a  = (bf16_t*)(ws + 10485760);   //  2,621,440  bf16 [4096][320]
  bf16_t* h1b  = (bf16_t*)(ws + 13107200);   //  2,621,440  bf16 [4096][320]
  float*  hbuf = (float*)(ws + 15728640);    //  5,242,880  f32  [4096][320]
  float*  x2   = (float*)(ws + 20971520);    //  5,242,880  f32  [4096][320]
  float*  q2   = (float*)(ws + 26214400);    //  5,242,880  f32  [4096][320]
  float*  kv2  = (float*)(ws + 31457280);    //    197,120  f32  [77][640]
  bf16_t* o2   = (bf16_t*)(ws + 31654400);   //  2,621,440  bf16 [4096][320]
  float*  x3   = (float*)(ws + 34275840);    //  5,242,880  f32  [4096][320]
  bf16_t* h3b  = (bf16_t*)(ws + 39518720);   //  2,621,440  bf16 [4096][320]
  bf16_t* wqkvt = (bf16_t*)(ws + 42140160);  //    614,400  bf16 [960][320]
  bf16_t* wo1t  = (bf16_t*)(ws + 42754560);  //    204,800  bf16 [320][320]
  float*  wkv2  = (float*)(ws + 42959360);   //  1,966,080  f32  [768][640]
  bf16_t* wo2t  = (bf16_t*)(ws + 44925440);  //    204,800
  bf16_t* wff1t = (bf16_t*)(ws + 45130240);  //  1,638,400
  bf16_t* wff2t = (bf16_t*)(ws + 46768640);  //    819,200  -> end 47,587,840
  bf16_t* proj = (bf16_t*)(ws + 0);          // 20,971,520  bf16 [4096][2560] (overlaps qkvb..hbuf)
  bf16_t* gg   = (bf16_t*)(ws + 20971520);   // 10,485,760  bf16 [4096][1280] (overlaps x2,q2)

  float* xout = (float*)d_out;

  prep_kernel<<<1024, 256, 0, stream>>>(Wq1, Wk1, Wv1, Wo1, Wk2, Wv2, Wo2, Wff1, Wff2,
                                        wqkvt, wo1t, wkv2, wo2t, wff1t, wff2t);
  // --- attn1 (bf16 MFMA flash; fca-safe per error analysis) ---
  ln_kernel<bf16_t><<<1024, 256, 0, stream>>>(x, g1, b1, h1b);
  gemm_bf16_kernel<1><<<dim3(32,15), 256, 0, stream>>>(h1b, wqkvt, nullptr, nullptr, qkvb, 4096, 960, 320);
  repack_vt_kernel<<<dim3(64,8), 256, 0, stream>>>(qkvb, vtg);
  flash_self_kernel<<<dim3(64,8), 256, 0, stream>>>(qkvb, vtg, o1a);
  gemm_bf16_kernel<0><<<dim3(32,5), 256, 0, stream>>>(o1a, wo1t, bo1, x, x2, 4096, 320, 320);
  // --- attn2 (sim2/fca path stays fp32) ---
  ln_kernel<float><<<1024, 256, 0, stream>>>(x2, g2, b2, hbuf);
  gemm_f32<<<dim3(32,5), 256, 0, stream>>>(hbuf, Wq2, nullptr, nullptr, q2, 4096, 320, 320);
  gemm_f32<<<dim3(1,10), 256, 0, stream>>>(ctx, wkv2, nullptr, nullptr, kv2, 77, 640, 768);
  attn_cross_kernel<<<dim3(128,8), 256, 0, stream>>>(q2, kv2, fam, ufca, o2);
  gemm_bf16_kernel<0><<<dim3(32,5), 256, 0, stream>>>(o2, wo2t, bo2, x2, x3, 4096, 320, 320);
  // --- GEGLU FF ---
  ln_kernel<bf16_t><<<1024, 256, 0, stream>>>(x3, g3, b3, h3b);
  gemm_bf16_kernel<1><<<dim3(32,40), 256, 0, stream>>>(h3b, wff1t, bff1, nullptr, proj, 4096, 2560, 320);
  geglu_kernel<<<5120, 256, 0, stream>>>(proj, gg);
  gemm_bf16_kernel<0><<<dim3(32,5), 256, 0, stream>>>(gg, wff2t, bff2, x3, xout, 4096, 320, 1280);
}

// Round 3
// 519.514 us; speedup vs baseline: 3.5140x; 1.1377x over previous
//
#include <hip/hip_runtime.h>
#include <math.h>

typedef __bf16 bf16_t;
typedef __bf16 bf16x8 __attribute__((ext_vector_type(8)));
typedef __bf16 bf16x4 __attribute__((ext_vector_type(4)));
typedef float  f32x4  __attribute__((ext_vector_type(4)));
typedef short  s16x4  __attribute__((ext_vector_type(4)));

static constexpr float ATT_SCALE = 0.15811388300841897f; // 40^-0.5
static constexpr float SC2 = 0.22811031f;                // ATT_SCALE * log2(e)

__device__ __forceinline__ bf16_t f2b(float f) {
  unsigned u = __float_as_uint(f);
  u = (u + 0x7fffu + ((u >> 16) & 1u)) >> 16;   // RNE
  unsigned short s = (unsigned short)u;
  bf16_t r;
  *(unsigned short*)&r = s;
  return r;
}
__device__ __forceinline__ float b2f(bf16_t b) {
  unsigned short s = *(const unsigned short*)&b;
  return __uint_as_float(((unsigned)s) << 16);
}
__device__ __forceinline__ void sto(float v, float* p)  { *p = v; }
__device__ __forceinline__ void sto(float v, bf16_t* p) { *p = f2b(v); }
// pack two floats to bf16 pair (round-to-nearest, ties-up: bias negligible for attn P)
__device__ __forceinline__ unsigned pk2(float a, float b) {
  unsigned ua = (__float_as_uint(a) + 0x8000u) >> 16;
  unsigned ub = (__float_as_uint(b) + 0x8000u) & 0xffff0000u;
  return ua | ub;
}

// =========================== weight repack ===========================
__global__ __launch_bounds__(256) void prep_kernel(
    const float* __restrict__ Wq1, const float* __restrict__ Wk1, const float* __restrict__ Wv1,
    const float* __restrict__ Wo1,
    const float* __restrict__ Wk2, const float* __restrict__ Wv2, const float* __restrict__ Wo2,
    const float* __restrict__ Wff1, const float* __restrict__ Wff2,
    bf16_t* __restrict__ wqkvt, bf16_t* __restrict__ wo1t, float* __restrict__ wkv2,
    bf16_t* __restrict__ wo2t, bf16_t* __restrict__ wff1t, bf16_t* __restrict__ wff2t)
{
  const int T1 = 960*320;
  const int T2 = T1 + 320*320;
  const int T3 = T2 + 768*640;
  const int T4 = T3 + 320*320;
  const int T5 = T4 + 2560*320;
  const int T6 = T5 + 320*1280;
  for (int i = blockIdx.x*256 + threadIdx.x; i < T6; i += gridDim.x*256) {
    if (i < T1) {
      int n = i / 320, k = i - n*320;
      float v = (n < 320) ? Wq1[k*320+n] : (n < 640) ? Wk1[k*320+n-320] : Wv1[k*320+n-640];
      wqkvt[i] = f2b(v);
    } else if (i < T2) {
      int e = i - T1; int n = e / 320, k = e - n*320;
      wo1t[e] = f2b(Wo1[k*320+n]);
    } else if (i < T3) {
      int e = i - T2; int k = e / 640, n = e - k*640;
      wkv2[e] = (n < 320) ? Wk2[k*320+n] : Wv2[k*320+n-320];
    } else if (i < T4) {
      int e = i - T3; int n = e / 320, k = e - n*320;
      wo2t[e] = f2b(Wo2[k*320+n]);
    } else if (i < T5) {
      int e = i - T4; int n = e / 320, k = e - n*320;
      wff1t[e] = f2b(Wff1[(size_t)k*2560+n]);
    } else {
      int e = i - T5; int n = e / 1280, k = e - n*1280;
      wff2t[e] = f2b(Wff2[k*320+n]);
    }
  }
}

// =========================== LayerNorm ===========================
template<typename OT>
__global__ __launch_bounds__(256) void ln_kernel(
    const float* __restrict__ x, const float* __restrict__ g, const float* __restrict__ b,
    OT* __restrict__ out)
{
  const int lane = threadIdx.x & 63;
  const int row = blockIdx.x * 4 + (threadIdx.x >> 6);
  const float* xr = x + (size_t)row * 320;
  float v[5], s = 0.f, s2 = 0.f;
#pragma unroll
  for (int i = 0; i < 5; i++) { v[i] = xr[lane + i*64]; s += v[i]; s2 += v[i]*v[i]; }
#pragma unroll
  for (int o = 32; o; o >>= 1) { s += __shfl_xor(s, o); s2 += __shfl_xor(s2, o); }
  float mu = s * (1.f/320.f);
  float rs = rsqrtf(fmaxf(s2*(1.f/320.f) - mu*mu, 0.f) + 1e-5f);
#pragma unroll
  for (int i = 0; i < 5; i++) {
    int c = lane + i*64;
    sto((v[i]-mu)*rs*g[c] + b[c], &out[(size_t)row*320 + c]);
  }
}

// =========================== fp32 GEMM ===========================
__global__ __launch_bounds__(256) void gemm_f32(
    const float* __restrict__ A, const float* __restrict__ B,
    const float* __restrict__ bias, const float* __restrict__ resid,
    float* __restrict__ C, int M, int N, int K)
{
  __shared__ float As[8][128];
  __shared__ float Bs[8][64];
  const int tid = threadIdx.x;
  const int m0 = blockIdx.x * 128, n0 = blockIdx.y * 64;
  const int tx = tid & 15, ty = tid >> 4;
  float acc[2][4][4] = {};
  for (int k0 = 0; k0 < K; k0 += 8) {
    __syncthreads();
    {
      int m = tid >> 1, kk = (tid & 1) * 4;
      int gm = m0 + m;
      float4 av = make_float4(0.f, 0.f, 0.f, 0.f);
      if (gm < M) av = *(const float4*)(A + (size_t)gm*K + k0 + kk);
      As[kk+0][m] = av.x; As[kk+1][m] = av.y; As[kk+2][m] = av.z; As[kk+3][m] = av.w;
    }
    if (tid < 128) {
      int kk = tid >> 4, nn = (tid & 15) * 4;
      *(float4*)&Bs[kk][nn] = *(const float4*)(B + (size_t)(k0+kk)*N + n0 + nn);
    }
    __syncthreads();
#pragma unroll
    for (int kk = 0; kk < 8; kk++) {
      float4 b4 = *(const float4*)&Bs[kk][tx*4];
      float4 a0 = *(const float4*)&As[kk][ty*4];
      float4 a1 = *(const float4*)&As[kk][64 + ty*4];
      float ar[2][4] = {{a0.x,a0.y,a0.z,a0.w},{a1.x,a1.y,a1.z,a1.w}};
      float br[4] = {b4.x,b4.y,b4.z,b4.w};
#pragma unroll
      for (int r = 0; r < 2; r++)
#pragma unroll
        for (int i = 0; i < 4; i++)
#pragma unroll
          for (int j = 0; j < 4; j++)
            acc[r][i][j] += ar[r][i] * br[j];
    }
  }
#pragma unroll
  for (int r = 0; r < 2; r++)
#pragma unroll
    for (int i = 0; i < 4; i++) {
      int gm = m0 + r*64 + ty*4 + i;
      if (gm >= M) continue;
#pragma unroll
      for (int j = 0; j < 4; j++) {
        int gn = n0 + tx*4 + j;
        float v = acc[r][i][j];
        if (bias)  v += bias[gn];
        if (resid) v += resid[(size_t)gm*N + gn];
        C[(size_t)gm*N + gn] = v;
      }
    }
}

// =========================== V^T repack: qkvb [4096][960] -> vtg [8][40][4096] ===========================
__global__ __launch_bounds__(256) void repack_vt_kernel(
    const bf16_t* __restrict__ qkvb, bf16_t* __restrict__ vtg)
{
  __shared__ bf16_t T[64*44];
  const int tid = threadIdx.x;
  const int t0 = blockIdx.x * 64, h = blockIdx.y;
  for (int e = tid; e < 320; e += 256) {
    int t = e / 5, c8 = (e - t*5) * 8;
    *(bf16x8*)&T[t*44 + c8] = *(const bf16x8*)(qkvb + (size_t)(t0+t)*960 + 640 + h*40 + c8);
  }
  __syncthreads();
  for (int e = tid; e < 320; e += 256) {
    int d = e >> 3, t8 = (e & 7) * 8;
    bf16x8 v;
#pragma unroll
    for (int j = 0; j < 8; j++) v[j] = T[(t8+j)*44 + d];
    *(bf16x8*)&vtg[((size_t)h*40 + d)*4096 + t0 + t8] = v;
  }
}

// =========================== bf16 MFMA flash self-attention (v2) ===========================
// S^T = K·Q^T  (16x16x32): C/D layout of S^T == B-operand layout of 16x16x16 MFMA,
// so P^T feeds O^T = V^T·P^T directly from registers. No max-tracking (logits bounded,
// softmax shift-invariant => exact). No LDS / barriers in K-loop; waves own key-slices.
// grid (64 q-blocks, 8 heads, 2 K-splits); block: 64 q-rows, wave w owns keys w*16..+15 of each tile.
__global__ __launch_bounds__(256, 4) void flash_self_kernel(
    const bf16_t* __restrict__ qkvb, const bf16_t* __restrict__ vtg,
    float* __restrict__ opart, float* __restrict__ lpart)
{
  __shared__ float Red[6144];      // 24 KB: [w][e][dt][q=ln][drow]
  __shared__ float Lred[4][64];
  const int tid = threadIdx.x;
  const int w = tid >> 6, lane = tid & 63;
  const int ln = lane & 15, qd = lane >> 4;
  const int h = blockIdx.y;
  const int q0 = blockIdx.x * 64;
  const int split = blockIdx.z;

  // Q B-frags for 4 n-tiles (n = q = nt*16+ln, k = d)
  bf16x8 zero8 = {};
  bf16x8 bq[4][2];
#pragma unroll
  for (int nt = 0; nt < 4; nt++) {
    const bf16_t* qp = qkvb + (size_t)(q0 + nt*16 + ln)*960 + h*40;
    bq[nt][0] = *(const bf16x8*)(qp + qd*8);
    bq[nt][1] = (qd == 0) ? *(const bf16x8*)(qp + 32) : zero8;
  }

  f32x4 zero4 = {0.f,0.f,0.f,0.f};
  f32x4 oacc[3][4];                // [dt][nt]  O^T partial (rows d, cols q)
#pragma unroll
  for (int a = 0; a < 3; a++)
#pragma unroll
    for (int b = 0; b < 4; b++) oacc[a][b] = zero4;
  float l_acc[4] = {0.f,0.f,0.f,0.f};

  const bf16_t* kbase = qkvb + 320 + h*40;
  const bf16_t* vbase = vtg + (size_t)h*40*4096;

  for (int kt = 0; kt < 32; kt++) {
    int k0 = split*2048 + kt*64;
    int krow = k0 + w*16 + ln;
    const bf16_t* kp = kbase + (size_t)krow*960;
    bf16x8 ka0 = *(const bf16x8*)(kp + qd*8);
    bf16x8 ka1 = (qd == 0) ? *(const bf16x8*)(kp + 32) : zero8;

    // S^T tiles (m = this wave's 16 keys, n = q), then p = exp2(s*SC2)
    uint2 ppk[4];
#pragma unroll
    for (int nt = 0; nt < 4; nt++) {
      f32x4 s = __builtin_amdgcn_mfma_f32_16x16x32_bf16(ka0, bq[nt][0], zero4, 0, 0, 0);
      s = __builtin_amdgcn_mfma_f32_16x16x32_bf16(ka1, bq[nt][1], s, 0, 0, 0);
      float p0 = __builtin_amdgcn_exp2f(s[0]*SC2);
      float p1 = __builtin_amdgcn_exp2f(s[1]*SC2);
      float p2 = __builtin_amdgcn_exp2f(s[2]*SC2);
      float p3 = __builtin_amdgcn_exp2f(s[3]*SC2);
      l_acc[nt] += (p0+p1)+(p2+p3);
      ppk[nt].x = pk2(p0, p1);
      ppk[nt].y = pk2(p2, p3);
    }
    // O^T += V^T · P^T : K=16 MFMA, A = V^T (m=d, k=wave's keys), B = P^T from regs
#pragma unroll
    for (int dt = 0; dt < 3; dt++) {
      const bf16_t* vp = vbase + (size_t)(dt*16+ln)*4096 + k0 + w*16 + qd*4;
      s16x4 va = *(const s16x4*)vp;   // rows d>=40 read scratch garbage; those C/D rows are discarded
#pragma unroll
      for (int nt = 0; nt < 4; nt++) {
        s16x4 pb = *(const s16x4*)&ppk[nt];
        oacc[dt][nt] = __builtin_amdgcn_mfma_f32_16x16x16bf16_1k(va, pb, oacc[dt][nt], 0, 0, 0);
      }
    }
  }

  // ---- epilogue: reduce across quads (keys) then across waves ----
#pragma unroll
  for (int nt = 0; nt < 4; nt++) {
    l_acc[nt] += __shfl_xor(l_acc[nt], 16);
    l_acc[nt] += __shfl_xor(l_acc[nt], 32);
  }
  if (qd == 0) {
#pragma unroll
    for (int nt = 0; nt < 4; nt++) Lred[w][nt*16 + ln] = l_acc[nt];
  }
  __syncthreads();
  if (tid < 64) {
    float lt = Lred[0][tid] + Lred[1][tid] + Lred[2][tid] + Lred[3][tid];
    lpart[(size_t)(split*8 + h)*4096 + q0 + tid] = lt;
  }
  float* obase = opart + ((size_t)(split*8 + h)*4096 + q0)*40;
  for (int np = 0; np < 2; np++) {
    __syncthreads();
#pragma unroll
    for (int e = 0; e < 2; e++) {
      int nt = np*2 + e;
#pragma unroll
      for (int dt = 0; dt < 3; dt++)
        *(f32x4*)&Red[(((w*2+e)*3 + dt)*16 + ln)*16 + qd*4] = oacc[dt][nt];
    }
    __syncthreads();
    int e = tid >> 7;            // 0..1
    int lq = (tid >> 3) & 15;    // q within n-tile
    int dbase = tid & 7;
#pragma unroll
    for (int i = 0; i < 5; i++) {
      int d = dbase + i*8;       // 0..39
      int dt = d >> 4, drow = d & 15;
      float v = Red[((0*2+e)*3 + dt)*256 + lq*16 + drow]
              + Red[((1*2+e)*3 + dt)*256 + lq*16 + drow]
              + Red[((2*2+e)*3 + dt)*256 + lq*16 + drow]
              + Red[((3*2+e)*3 + dt)*256 + lq*16 + drow];
      obase[(size_t)((np*2+e)*16 + lq)*40 + d] = v;
    }
  }
}

// =========================== merge K-split partials ===========================
__global__ __launch_bounds__(256) void merge_o1_kernel(
    const float* __restrict__ op, const float* __restrict__ lp, bf16_t* __restrict__ o1a)
{
  int i = blockIdx.x*256 + threadIdx.x;     // 4096*320
  int q = i / 320, c = i - q*320;
  int h = c / 40, d = c - h*40;
  size_t base = ((size_t)h*4096 + q)*40 + d;
  float l = lp[h*4096 + q] + lp[32768 + h*4096 + q];
  float o = op[base] + op[base + 1310720];
  o1a[i] = f2b(o / l);
}

// =========================== cross-attention with focused-attention mask ===========================
__global__ __launch_bounds__(256) void attn_cross_kernel(
    const float* __restrict__ q2, const float* __restrict__ kv2,
    const float* __restrict__ fam, const int* __restrict__ use_fca,
    bf16_t* __restrict__ o2)
{
  __shared__ float Kt[40*128];
  __shared__ float Vsh[77*41];
  __shared__ float fams[77*81];
  __shared__ float simb[4*96];
  const int tid = threadIdx.x;
  const int h = blockIdx.y;
  const int q0 = blockIdx.x * 32;
  const int wid = tid >> 6, lane = tid & 63;

  for (int e = tid; e < 40*128; e += 256) Kt[e] = 0.f;
  __syncthreads();
  for (int e = tid; e < 77*40; e += 256) {
    int j = e / 40, d = e - j*40;
    Kt[d*128 + j] = kv2[(size_t)j*640 + h*40 + d];
    Vsh[j*41 + d] = kv2[(size_t)j*640 + 320 + h*40 + d];
  }
  for (int e = tid; e < 77*77; e += 256) {
    int d = e / 77;
    fams[e + d*4] = fam[e];
  }
  __syncthreads();

  const int fca = use_fca[0];
  const bool v1 = (64 + lane) < 77;
  float* sb = simb + wid*96;
  const float* fr0 = fams + lane*81;
  const float* fr1 = fams + (v1 ? (64+lane) : 76)*81;

  for (int it = 0; it < 8; it++) {
    int row = q0 + wid*8 + it;
    float qv = (lane < 40) ? q2[(size_t)row*320 + h*40 + lane] : 0.f;
    float s0 = 0.f, s1 = 0.f;
#pragma unroll
    for (int d = 0; d < 40; d++) {
      float qd = __shfl(qv, d);
      s0 += qd * Kt[d*128 + lane];
      s1 += qd * Kt[d*128 + 64 + lane];
    }
    s0 *= ATT_SCALE; s1 *= ATT_SCALE;
    if (fca) {
      sb[lane] = s0;
      if (v1) sb[64+lane] = s1;
      float fw0 = 0.f, fw1 = 0.f;
      for (int k = 0; k < 77; k++) {
        float sk = sb[k];
        fw0 += sk * fr0[k];
        fw1 += sk * fr1[k];
      }
      fw0 = fminf(fabsf(fw0), 1.f);
      fw1 = v1 ? fminf(fabsf(fw1), 1.f) : 0.f;
      float fm = fmaxf(fw0, fw1);
#pragma unroll
      for (int off = 32; off; off >>= 1) fm = fmaxf(fm, __shfl_xor(fm, off));
      float den = fm + 1e-6f;
      if (!(fw0/den > 0.6f)) s0 -= 50.f;
      if (v1 && !(fw1/den > 0.6f)) s1 -= 50.f;
    }
    if (!v1) s1 = -1e30f;
    float mxv = fmaxf(s0, s1);
#pragma unroll
    for (int off = 32; off; off >>= 1) mxv = fmaxf(mxv, __shfl_xor(mxv, off));
    float p0 = __expf(s0 - mxv);
    float p1 = v1 ? __expf(s1 - mxv) : 0.f;
    float ps = p0 + p1;
#pragma unroll
    for (int off = 32; off; off >>= 1) ps += __shfl_xor(ps, off);
    sb[lane] = p0;
    if (v1) sb[64+lane] = p1;
    if (lane < 40) {
      float a = 0.f;
      for (int j = 0; j < 77; j++) a += sb[j] * Vsh[j*41 + lane];
      sto(a / ps, &o2[(size_t)row*320 + h*40 + lane]);
    }
  }
}

// =========================== bf16 MFMA GEMM: C = A[M][K] @ Bt[N][K]^T ===========================
template<int OUT_BF16>
__global__ __launch_bounds__(256) void gemm_bf16_kernel(
    const bf16_t* __restrict__ A, const bf16_t* __restrict__ Bt,
    const float* __restrict__ bias, const float* __restrict__ resid,
    void* __restrict__ Cout, int M, int N, int K)
{
  __shared__ bf16_t As[128][72];
  __shared__ bf16_t Bs[64][72];
  const int tid = threadIdx.x;
  const int m0 = blockIdx.x * 128, n0 = blockIdx.y * 64;
  const int w = tid >> 6, lane = tid & 63;
  const int wr = w >> 1, wc = w & 1;
  const int ln = lane & 15, qd = lane >> 4;
  f32x4 zero = {0.f, 0.f, 0.f, 0.f};
  f32x4 acc[4][2];
#pragma unroll
  for (int a = 0; a < 4; a++)
#pragma unroll
    for (int b = 0; b < 2; b++) acc[a][b] = zero;

  for (int k0 = 0; k0 < K; k0 += 64) {
    __syncthreads();
#pragma unroll
    for (int i = 0; i < 4; i++) {
      int vid = tid + i*256;
      int r = vid >> 3, c8 = (vid & 7) * 8;
      *(bf16x8*)&As[r][c8] = *(const bf16x8*)(A + (size_t)(m0+r)*K + k0 + c8);
    }
#pragma unroll
    for (int i = 0; i < 2; i++) {
      int vid = tid + i*256;
      int r = vid >> 3, c8 = (vid & 7) * 8;
      *(bf16x8*)&Bs[r][c8] = *(const bf16x8*)(Bt + (size_t)(n0+r)*K + k0 + c8);
    }
    __syncthreads();
#pragma unroll
    for (int c = 0; c < 2; c++) {
      bf16x8 af[4], bfr[2];
#pragma unroll
      for (int mt = 0; mt < 4; mt++)
        af[mt] = *(const bf16x8*)&As[wr*64 + mt*16 + ln][c*32 + qd*8];
#pragma unroll
      for (int nt = 0; nt < 2; nt++)
        bfr[nt] = *(const bf16x8*)&Bs[wc*32 + nt*16 + ln][c*32 + qd*8];
#pragma unroll
      for (int mt = 0; mt < 4; mt++)
#pragma unroll
        for (int nt = 0; nt < 2; nt++)
          acc[mt][nt] = __builtin_amdgcn_mfma_f32_16x16x32_bf16(af[mt], bfr[nt], acc[mt][nt], 0, 0, 0);
    }
  }
#pragma unroll
  for (int mt = 0; mt < 4; mt++)
#pragma unroll
    for (int nt = 0; nt < 2; nt++)
#pragma unroll
      for (int r = 0; r < 4; r++) {
        int gm = m0 + wr*64 + mt*16 + qd*4 + r;
        int gn = n0 + wc*32 + nt*16 + ln;
        float v = acc[mt][nt][r];
        if (bias)  v += bias[gn];
        if (resid) v += resid[(size_t)gm*N + gn];
        if (OUT_BF16) sto(v, &((bf16_t*)Cout)[(size_t)gm*N + gn]);
        else          sto(v, &((float*)Cout)[(size_t)gm*N + gn]);
      }
}

// =========================== GEGLU ===========================
__global__ __launch_bounds__(256) void geglu_kernel(
    const bf16_t* __restrict__ proj, bf16_t* __restrict__ gg)
{
  int idx = blockIdx.x * 256 + threadIdx.x;
  int m = idx / 320, c4 = (idx - m*320) * 4;
  bf16x4 a = *(const bf16x4*)(proj + (size_t)m*2560 + c4);
  bf16x4 g = *(const bf16x4*)(proj + (size_t)m*2560 + 1280 + c4);
  bf16x4 r;
#pragma unroll
  for (int i = 0; i < 4; i++) {
    float gf = b2f(g[i]);
    float ge = 0.5f * gf * (1.f + erff(gf * 0.70710678118654752f));
    r[i] = f2b(b2f(a[i]) * ge);
  }
  *(bf16x4*)(gg + (size_t)m*1280 + c4) = r;
}

// =========================== launch ===========================
extern "C" void kernel_launch(void* const* d_in, const int* in_sizes, int n_in,
                              void* d_out, int out_size, void* d_ws, size_t ws_size,
                              hipStream_t stream)
{
  const float* x    = (const float*)d_in[0];
  const float* ctx  = (const float*)d_in[1];
  const float* fam  = (const float*)d_in[2];
  const float* g1   = (const float*)d_in[3];
  const float* b1   = (const float*)d_in[4];
  const float* g2   = (const float*)d_in[5];
  const float* b2   = (const float*)d_in[6];
  const float* g3   = (const float*)d_in[7];
  const float* b3   = (const float*)d_in[8];
  const float* Wq1  = (const float*)d_in[9];
  const float* Wk1  = (const float*)d_in[10];
  const float* Wv1  = (const float*)d_in[11];
  const float* Wo1  = (const float*)d_in[12];
  const float* bo1  = (const float*)d_in[13];
  const float* Wq2  = (const float*)d_in[14];
  const float* Wk2  = (const float*)d_in[15];
  const float* Wv2  = (const float*)d_in[16];
  const float* Wo2  = (const float*)d_in[17];
  const float* bo2  = (const float*)d_in[18];
  const float* Wff1 = (const float*)d_in[19];
  const float* bff1 = (const float*)d_in[20];
  const float* Wff2 = (const float*)d_in[21];
  const float* bff2 = (const float*)d_in[22];
  const int*   ufca = (const int*)d_in[23];

  char* ws = (char*)d_ws;
  bf16_t* qkvb = (bf16_t*)(ws + 0);          //  7,864,320  bf16 [4096][960]
  bf16_t* vtg  = (bf16_t*)(ws + 7864320);    //  2,621,440  bf16 [8][40][4096]
  bf16_t* o1a  = (bf16_t*)(ws + 10485760);   //  2,621,440  bf16 [4096][320]
  bf16_t* h1b  = (bf16_t*)(ws + 13107200);   //  2,621,440  bf16 [4096][320]
  float*  hbuf = (float*)(ws + 15728640);    //  5,242,880  f32  [4096][320]
  float*  x2   = (float*)(ws + 20971520);    //  5,242,880  f32  [4096][320]
  float*  q2   = (float*)(ws + 26214400);    //  5,242,880  f32  [4096][320]
  float*  kv2  = (float*)(ws + 31457280);    //    197,120  f32  [77][640]
  bf16_t* o2   = (bf16_t*)(ws + 31654400);   //  2,621,440  bf16 [4096][320]
  float*  x3   = (float*)(ws + 34275840);    //  5,242,880  f32  [4096][320]
  bf16_t* h3b  = (bf16_t*)(ws + 39518720);   //  2,621,440  bf16 [4096][320]
  bf16_t* wqkvt = (bf16_t*)(ws + 42140160);  //    614,400
  bf16_t* wo1t  = (bf16_t*)(ws + 42754560);  //    204,800
  float*  wkv2  = (float*)(ws + 42959360);   //  1,966,080
  bf16_t* wo2t  = (bf16_t*)(ws + 44925440);  //    204,800
  bf16_t* wff1t = (bf16_t*)(ws + 45130240);  //  1,638,400
  bf16_t* wff2t = (bf16_t*)(ws + 46768640);  //    819,200
  float*  lpart = (float*)(ws + 47587840);   //    262,144  f32 [2][8][4096]  -> end 47,849,984
  // opart overlaps x2..h3b (all dead during flash+merge): f32 [2][8][4096][40] = 20,971,520 B
  float*  opart = (float*)(ws + 20971520);
  bf16_t* proj = (bf16_t*)(ws + 0);          // bf16 [4096][2560] (overlaps qkvb..hbuf, FF phase only)
  bf16_t* gg   = (bf16_t*)(ws + 20971520);   // bf16 [4096][1280] (overlaps x2,q2, FF phase only)

  float* xout = (float*)d_out;

  prep_kernel<<<1024, 256, 0, stream>>>(Wq1, Wk1, Wv1, Wo1, Wk2, Wv2, Wo2, Wff1, Wff2,
                                        wqkvt, wo1t, wkv2, wo2t, wff1t, wff2t);
  // --- attn1 (bf16 MFMA flash) ---
  ln_kernel<bf16_t><<<1024, 256, 0, stream>>>(x, g1, b1, h1b);
  gemm_bf16_kernel<1><<<dim3(32,15), 256, 0, stream>>>(h1b, wqkvt, nullptr, nullptr, qkvb, 4096, 960, 320);
  repack_vt_kernel<<<dim3(64,8), 256, 0, stream>>>(qkvb, vtg);
  flash_self_kernel<<<dim3(64,8,2), 256, 0, stream>>>(qkvb, vtg, opart, lpart);
  merge_o1_kernel<<<5120, 256, 0, stream>>>(opart, lpart, o1a);
  gemm_bf16_kernel<0><<<dim3(32,5), 256, 0, stream>>>(o1a, wo1t, bo1, x, x2, 4096, 320, 320);
  // --- attn2 (sim2/fca path stays fp32) ---
  ln_kernel<float><<<1024, 256, 0, stream>>>(x2, g2, b2, hbuf);
  gemm_f32<<<dim3(32,5), 256, 0, stream>>>(hbuf, Wq2, nullptr, nullptr, q2, 4096, 320, 320);
  gemm_f32<<<dim3(1,10), 256, 0, stream>>>(ctx, wkv2, nullptr, nullptr, kv2, 77, 640, 768);
  attn_cross_kernel<<<dim3(128,8), 256, 0, stream>>>(q2, kv2, fam, ufca, o2);
  gemm_bf16_kernel<0><<<dim3(32,5), 256, 0, stream>>>(o2, wo2t, bo2, x2, x3, 4096, 320, 320);
  // --- GEGLU FF ---
  ln_kernel<bf16_t><<<1024, 256, 0, stream>>>(x3, g3, b3, h3b);
  gemm_bf16_kernel<1><<<dim3(32,40), 256, 0, stream>>>(h3b, wff1t, bff1, nullptr, proj, 4096, 2560, 320);
  geglu_kernel<<<5120, 256, 0, stream>>>(proj, gg);
  gemm_bf16_kernel<0><<<dim3(32,5), 256, 0, stream>>>(gg, wff2t, bff2, x3, xout, 4096, 320, 1280);
}

// Round 4
// 411.650 us; speedup vs baseline: 4.4348x; 1.2620x over previous
//
#include <hip/hip_runtime.h>
#include <math.h>

typedef __bf16 bf16_t;
typedef __bf16 bf16x8 __attribute__((ext_vector_type(8)));
typedef __bf16 bf16x4 __attribute__((ext_vector_type(4)));
typedef float  f32x4  __attribute__((ext_vector_type(4)));
typedef short  s16x4  __attribute__((ext_vector_type(4)));

static constexpr float ATT_SCALE = 0.15811388300841897f; // 40^-0.5
static constexpr float SC2 = 0.22811031f;                // ATT_SCALE * log2(e)

__device__ __forceinline__ bf16_t f2b(float f) {
  unsigned u = __float_as_uint(f);
  u = (u + 0x7fffu + ((u >> 16) & 1u)) >> 16;   // RNE
  unsigned short s = (unsigned short)u;
  bf16_t r;
  *(unsigned short*)&r = s;
  return r;
}
__device__ __forceinline__ float b2f(bf16_t b) {
  unsigned short s = *(const unsigned short*)&b;
  return __uint_as_float(((unsigned)s) << 16);
}
__device__ __forceinline__ void sto(float v, float* p)  { *p = v; }
__device__ __forceinline__ void sto(float v, bf16_t* p) { *p = f2b(v); }
__device__ __forceinline__ unsigned pk2(float a, float b) {
  unsigned ua = (__float_as_uint(a) + 0x8000u) >> 16;
  unsigned ub = (__float_as_uint(b) + 0x8000u) & 0xffff0000u;
  return ua | ub;
}

// =========================== weight repack ===========================
// wqkvt bf16 [960][320]; wo1t bf16 [320][320]; wkv2t f32 [640][768] (row n = col of [Wk2|Wv2]);
// wo2t bf16 [320][320]; wff1t bf16 [2560][320]; wff2t bf16 [320][1280];
// wq2t hi/lo bf16 [320][320] (fp32-emulation split of Wq2^T).
__global__ __launch_bounds__(256) void prep_kernel(
    const float* __restrict__ Wq1, const float* __restrict__ Wk1, const float* __restrict__ Wv1,
    const float* __restrict__ Wo1, const float* __restrict__ Wq2,
    const float* __restrict__ Wk2, const float* __restrict__ Wv2, const float* __restrict__ Wo2,
    const float* __restrict__ Wff1, const float* __restrict__ Wff2,
    bf16_t* __restrict__ wqkvt, bf16_t* __restrict__ wo1t, float* __restrict__ wkv2t,
    bf16_t* __restrict__ wo2t, bf16_t* __restrict__ wff1t, bf16_t* __restrict__ wff2t,
    bf16_t* __restrict__ wq2th, bf16_t* __restrict__ wq2tl)
{
  const int T1 = 960*320;
  const int T2 = T1 + 320*320;
  const int T3 = T2 + 768*640;
  const int T4 = T3 + 320*320;
  const int T5 = T4 + 2560*320;
  const int T6 = T5 + 320*1280;
  const int T7 = T6 + 320*320;
  for (int i = blockIdx.x*256 + threadIdx.x; i < T7; i += gridDim.x*256) {
    if (i < T1) {
      int n = i / 320, k = i - n*320;
      float v = (n < 320) ? Wq1[k*320+n] : (n < 640) ? Wk1[k*320+n-320] : Wv1[k*320+n-640];
      wqkvt[i] = f2b(v);
    } else if (i < T2) {
      int e = i - T1; int n = e / 320, k = e - n*320;
      wo1t[e] = f2b(Wo1[k*320+n]);
    } else if (i < T3) {
      int e = i - T2; int n = e / 768, k = e - n*768;
      wkv2t[e] = (n < 320) ? Wk2[k*320+n] : Wv2[k*320+n-320];
    } else if (i < T4) {
      int e = i - T3; int n = e / 320, k = e - n*320;
      wo2t[e] = f2b(Wo2[k*320+n]);
    } else if (i < T5) {
      int e = i - T4; int n = e / 320, k = e - n*320;
      wff1t[e] = f2b(Wff1[(size_t)k*2560+n]);
    } else if (i < T6) {
      int e = i - T5; int n = e / 1280, k = e - n*1280;
      wff2t[e] = f2b(Wff2[k*320+n]);
    } else {
      int e = i - T6; int n = e / 320, k = e - n*320;
      float v = Wq2[k*320+n];
      bf16_t h = f2b(v);
      wq2th[e] = h;
      wq2tl[e] = f2b(v - b2f(h));
    }
  }
}

// =========================== LayerNorm ===========================
template<typename OT>
__global__ __launch_bounds__(256) void ln_kernel(
    const float* __restrict__ x, const float* __restrict__ g, const float* __restrict__ b,
    OT* __restrict__ out)
{
  const int lane = threadIdx.x & 63;
  const int row = blockIdx.x * 4 + (threadIdx.x >> 6);
  const float* xr = x + (size_t)row * 320;
  float v[5], s = 0.f, s2 = 0.f;
#pragma unroll
  for (int i = 0; i < 5; i++) { v[i] = xr[lane + i*64]; s += v[i]; s2 += v[i]*v[i]; }
#pragma unroll
  for (int o = 32; o; o >>= 1) { s += __shfl_xor(s, o); s2 += __shfl_xor(s2, o); }
  float mu = s * (1.f/320.f);
  float rs = rsqrtf(fmaxf(s2*(1.f/320.f) - mu*mu, 0.f) + 1e-5f);
#pragma unroll
  for (int i = 0; i < 5; i++) {
    int c = lane + i*64;
    sto((v[i]-mu)*rs*g[c] + b[c], &out[(size_t)row*320 + c]);
  }
}

// LayerNorm writing hi/lo bf16 split (fp32 emulation input for gemm3)
__global__ __launch_bounds__(256) void ln2_split_kernel(
    const float* __restrict__ x, const float* __restrict__ g, const float* __restrict__ b,
    bf16_t* __restrict__ hi, bf16_t* __restrict__ lo)
{
  const int lane = threadIdx.x & 63;
  const int row = blockIdx.x * 4 + (threadIdx.x >> 6);
  const float* xr = x + (size_t)row * 320;
  float v[5], s = 0.f, s2 = 0.f;
#pragma unroll
  for (int i = 0; i < 5; i++) { v[i] = xr[lane + i*64]; s += v[i]; s2 += v[i]*v[i]; }
#pragma unroll
  for (int o = 32; o; o >>= 1) { s += __shfl_xor(s, o); s2 += __shfl_xor(s2, o); }
  float mu = s * (1.f/320.f);
  float rs = rsqrtf(fmaxf(s2*(1.f/320.f) - mu*mu, 0.f) + 1e-5f);
#pragma unroll
  for (int i = 0; i < 5; i++) {
    int c = lane + i*64;
    float y = (v[i]-mu)*rs*g[c] + b[c];
    bf16_t h = f2b(y);
    hi[(size_t)row*320 + c] = h;
    lo[(size_t)row*320 + c] = f2b(y - b2f(h));
  }
}

// =========================== kv2 dot-product GEMM: kv2[77][640] = ctx[77][768] @ wkv2t[640][768]^T ===========================
// one 16-lane group per output element; exact fp32.
__global__ __launch_bounds__(256) void kv2_dot_kernel(
    const float* __restrict__ ctx, const float* __restrict__ wkv2t, float* __restrict__ kv2)
{
  const int gid = blockIdx.x*16 + (threadIdx.x >> 4);
  const int q = threadIdx.x & 15;
  const int m = gid / 640, n = gid - m*640;
  const float4* a = (const float4*)(ctx + (size_t)m*768);
  const float4* b = (const float4*)(wkv2t + (size_t)n*768);
  float acc = 0.f;
#pragma unroll
  for (int i = 0; i < 12; i++) {
    float4 av = a[i*16+q], bv = b[i*16+q];
    acc += av.x*bv.x + av.y*bv.y + av.z*bv.z + av.w*bv.w;
  }
#pragma unroll
  for (int o = 8; o; o >>= 1) acc += __shfl_xor(acc, o);
  if (q == 0) kv2[(size_t)m*640 + n] = acc;
}

// =========================== V^T repack ===========================
__global__ __launch_bounds__(256) void repack_vt_kernel(
    const bf16_t* __restrict__ qkvb, bf16_t* __restrict__ vtg)
{
  __shared__ bf16_t T[64*44];
  const int tid = threadIdx.x;
  const int t0 = blockIdx.x * 64, h = blockIdx.y;
  for (int e = tid; e < 320; e += 256) {
    int t = e / 5, c8 = (e - t*5) * 8;
    *(bf16x8*)&T[t*44 + c8] = *(const bf16x8*)(qkvb + (size_t)(t0+t)*960 + 640 + h*40 + c8);
  }
  __syncthreads();
  for (int e = tid; e < 320; e += 256) {
    int d = e >> 3, t8 = (e & 7) * 8;
    bf16x8 v;
#pragma unroll
    for (int j = 0; j < 8; j++) v[j] = T[(t8+j)*44 + d];
    *(bf16x8*)&vtg[((size_t)h*40 + d)*4096 + t0 + t8] = v;
  }
}

// =========================== bf16 MFMA flash self-attention ===========================
__global__ __launch_bounds__(256, 4) void flash_self_kernel(
    const bf16_t* __restrict__ qkvb, const bf16_t* __restrict__ vtg,
    float* __restrict__ opart, float* __restrict__ lpart)
{
  __shared__ float Red[6144];
  __shared__ float Lred[4][64];
  const int tid = threadIdx.x;
  const int w = tid >> 6, lane = tid & 63;
  const int ln = lane & 15, qd = lane >> 4;
  const int h = blockIdx.y;
  const int q0 = blockIdx.x * 64;
  const int split = blockIdx.z;

  bf16x8 zero8 = {};
  bf16x8 bq[4][2];
#pragma unroll
  for (int nt = 0; nt < 4; nt++) {
    const bf16_t* qp = qkvb + (size_t)(q0 + nt*16 + ln)*960 + h*40;
    bq[nt][0] = *(const bf16x8*)(qp + qd*8);
    bq[nt][1] = (qd == 0) ? *(const bf16x8*)(qp + 32) : zero8;
  }

  f32x4 zero4 = {0.f,0.f,0.f,0.f};
  f32x4 oacc[3][4];
#pragma unroll
  for (int a = 0; a < 3; a++)
#pragma unroll
    for (int b = 0; b < 4; b++) oacc[a][b] = zero4;
  float l_acc[4] = {0.f,0.f,0.f,0.f};

  const bf16_t* kbase = qkvb + 320 + h*40;
  const bf16_t* vbase = vtg + (size_t)h*40*4096;

  for (int kt = 0; kt < 32; kt++) {
    int k0 = split*2048 + kt*64;
    int krow = k0 + w*16 + ln;
    const bf16_t* kp = kbase + (size_t)krow*960;
    bf16x8 ka0 = *(const bf16x8*)(kp + qd*8);
    bf16x8 ka1 = (qd == 0) ? *(const bf16x8*)(kp + 32) : zero8;

    uint2 ppk[4];
#pragma unroll
    for (int nt = 0; nt < 4; nt++) {
      f32x4 s = __builtin_amdgcn_mfma_f32_16x16x32_bf16(ka0, bq[nt][0], zero4, 0, 0, 0);
      s = __builtin_amdgcn_mfma_f32_16x16x32_bf16(ka1, bq[nt][1], s, 0, 0, 0);
      float p0 = __builtin_amdgcn_exp2f(s[0]*SC2);
      float p1 = __builtin_amdgcn_exp2f(s[1]*SC2);
      float p2 = __builtin_amdgcn_exp2f(s[2]*SC2);
      float p3 = __builtin_amdgcn_exp2f(s[3]*SC2);
      l_acc[nt] += (p0+p1)+(p2+p3);
      ppk[nt].x = pk2(p0, p1);
      ppk[nt].y = pk2(p2, p3);
    }
#pragma unroll
    for (int dt = 0; dt < 3; dt++) {
      const bf16_t* vp = vbase + (size_t)(dt*16+ln)*4096 + k0 + w*16 + qd*4;
      s16x4 va = *(const s16x4*)vp;
#pragma unroll
      for (int nt = 0; nt < 4; nt++) {
        s16x4 pb = *(const s16x4*)&ppk[nt];
        oacc[dt][nt] = __builtin_amdgcn_mfma_f32_16x16x16bf16_1k(va, pb, oacc[dt][nt], 0, 0, 0);
      }
    }
  }

#pragma unroll
  for (int nt = 0; nt < 4; nt++) {
    l_acc[nt] += __shfl_xor(l_acc[nt], 16);
    l_acc[nt] += __shfl_xor(l_acc[nt], 32);
  }
  if (qd == 0) {
#pragma unroll
    for (int nt = 0; nt < 4; nt++) Lred[w][nt*16 + ln] = l_acc[nt];
  }
  __syncthreads();
  if (tid < 64) {
    float lt = Lred[0][tid] + Lred[1][tid] + Lred[2][tid] + Lred[3][tid];
    lpart[(size_t)(split*8 + h)*4096 + q0 + tid] = lt;
  }
  float* obase = opart + ((size_t)(split*8 + h)*4096 + q0)*40;
  for (int np = 0; np < 2; np++) {
    __syncthreads();
#pragma unroll
    for (int e = 0; e < 2; e++) {
      int nt = np*2 + e;
#pragma unroll
      for (int dt = 0; dt < 3; dt++)
        *(f32x4*)&Red[(((w*2+e)*3 + dt)*16 + ln)*16 + qd*4] = oacc[dt][nt];
    }
    __syncthreads();
    int e = tid >> 7;
    int lq = (tid >> 3) & 15;
    int dbase = tid & 7;
#pragma unroll
    for (int i = 0; i < 5; i++) {
      int d = dbase + i*8;
      int dt = d >> 4, drow = d & 15;
      float v = Red[((0*2+e)*3 + dt)*256 + lq*16 + drow]
              + Red[((1*2+e)*3 + dt)*256 + lq*16 + drow]
              + Red[((2*2+e)*3 + dt)*256 + lq*16 + drow]
              + Red[((3*2+e)*3 + dt)*256 + lq*16 + drow];
      obase[(size_t)((np*2+e)*16 + lq)*40 + d] = v;
    }
  }
}

// =========================== merge K-split partials ===========================
__global__ __launch_bounds__(256) void merge_o1_kernel(
    const float* __restrict__ op, const float* __restrict__ lp, bf16_t* __restrict__ o1a)
{
  int i = blockIdx.x*256 + threadIdx.x;
  int q = i / 320, c = i - q*320;
  int h = c / 40, d = c - h*40;
  size_t base = ((size_t)h*4096 + q)*40 + d;
  float l = lp[h*4096 + q] + lp[32768 + h*4096 + q];
  float o = op[base] + op[base + 1310720];
  o1a[i] = f2b(o / l);
}

// =========================== cross-attention with focused-attention mask ===========================
__global__ __launch_bounds__(256) void attn_cross_kernel(
    const float* __restrict__ q2, const float* __restrict__ kv2,
    const float* __restrict__ fam, const int* __restrict__ use_fca,
    bf16_t* __restrict__ o2)
{
  __shared__ float Kt[40*128];
  __shared__ float Vsh[77*41];
  __shared__ float fams[77*81];
  __shared__ float simb[4*96];
  const int tid = threadIdx.x;
  const int h = blockIdx.y;
  const int q0 = blockIdx.x * 32;
  const int wid = tid >> 6, lane = tid & 63;

  for (int e = tid; e < 40*128; e += 256) Kt[e] = 0.f;
  __syncthreads();
  for (int e = tid; e < 77*40; e += 256) {
    int j = e / 40, d = e - j*40;
    Kt[d*128 + j] = kv2[(size_t)j*640 + h*40 + d];
    Vsh[j*41 + d] = kv2[(size_t)j*640 + 320 + h*40 + d];
  }
  for (int e = tid; e < 77*77; e += 256) {
    int d = e / 77;
    fams[e + d*4] = fam[e];
  }
  __syncthreads();

  const int fca = use_fca[0];
  const bool v1 = (64 + lane) < 77;
  float* sb = simb + wid*96;
  const float* fr0 = fams + lane*81;
  const float* fr1 = fams + (v1 ? (64+lane) : 76)*81;

  for (int it = 0; it < 8; it++) {
    int row = q0 + wid*8 + it;
    float qv = (lane < 40) ? q2[(size_t)row*320 + h*40 + lane] : 0.f;
    float s0 = 0.f, s1 = 0.f;
#pragma unroll
    for (int d = 0; d < 40; d++) {
      float qd = __shfl(qv, d);
      s0 += qd * Kt[d*128 + lane];
      s1 += qd * Kt[d*128 + 64 + lane];
    }
    s0 *= ATT_SCALE; s1 *= ATT_SCALE;
    if (fca) {
      sb[lane] = s0;
      if (v1) sb[64+lane] = s1;
      float fw0 = 0.f, fw1 = 0.f;
      for (int k = 0; k < 77; k++) {
        float sk = sb[k];
        fw0 += sk * fr0[k];
        fw1 += sk * fr1[k];
      }
      fw0 = fminf(fabsf(fw0), 1.f);
      fw1 = v1 ? fminf(fabsf(fw1), 1.f) : 0.f;
      float fm = fmaxf(fw0, fw1);
#pragma unroll
      for (int off = 32; off; off >>= 1) fm = fmaxf(fm, __shfl_xor(fm, off));
      float den = fm + 1e-6f;
      if (!(fw0/den > 0.6f)) s0 -= 50.f;
      if (v1 && !(fw1/den > 0.6f)) s1 -= 50.f;
    }
    if (!v1) s1 = -1e30f;
    float mxv = fmaxf(s0, s1);
#pragma unroll
    for (int off = 32; off; off >>= 1) mxv = fmaxf(mxv, __shfl_xor(mxv, off));
    float p0 = __expf(s0 - mxv);
    float p1 = v1 ? __expf(s1 - mxv) : 0.f;
    float ps = p0 + p1;
#pragma unroll
    for (int off = 32; off; off >>= 1) ps += __shfl_xor(ps, off);
    sb[lane] = p0;
    if (v1) sb[64+lane] = p1;
    if (lane < 40) {
      float a = 0.f;
      for (int j = 0; j < 77; j++) a += sb[j] * Vsh[j*41 + lane];
      sto(a / ps, &o2[(size_t)row*320 + h*40 + lane]);
    }
  }
}

// =========================== bf16 MFMA GEMM: C = A[M][K] @ Bt[N][K]^T ===========================
template<int OUT_BF16>
__global__ __launch_bounds__(256) void gemm_bf16_kernel(
    const bf16_t* __restrict__ A, const bf16_t* __restrict__ Bt,
    const float* __restrict__ bias, const float* __restrict__ resid,
    void* __restrict__ Cout, int M, int N, int K)
{
  __shared__ bf16_t As[128][72];
  __shared__ bf16_t Bs[64][72];
  const int tid = threadIdx.x;
  const int m0 = blockIdx.x * 128, n0 = blockIdx.y * 64;
  const int w = tid >> 6, lane = tid & 63;
  const int wr = w >> 1, wc = w & 1;
  const int ln = lane & 15, qd = lane >> 4;
  f32x4 zero = {0.f, 0.f, 0.f, 0.f};
  f32x4 acc[4][2];
#pragma unroll
  for (int a = 0; a < 4; a++)
#pragma unroll
    for (int b = 0; b < 2; b++) acc[a][b] = zero;

  for (int k0 = 0; k0 < K; k0 += 64) {
    __syncthreads();
#pragma unroll
    for (int i = 0; i < 4; i++) {
      int vid = tid + i*256;
      int r = vid >> 3, c8 = (vid & 7) * 8;
      *(bf16x8*)&As[r][c8] = *(const bf16x8*)(A + (size_t)(m0+r)*K + k0 + c8);
    }
#pragma unroll
    for (int i = 0; i < 2; i++) {
      int vid = tid + i*256;
      int r = vid >> 3, c8 = (vid & 7) * 8;
      *(bf16x8*)&Bs[r][c8] = *(const bf16x8*)(Bt + (size_t)(n0+r)*K + k0 + c8);
    }
    __syncthreads();
#pragma unroll
    for (int c = 0; c < 2; c++) {
      bf16x8 af[4], bfr[2];
#pragma unroll
      for (int mt = 0; mt < 4; mt++)
        af[mt] = *(const bf16x8*)&As[wr*64 + mt*16 + ln][c*32 + qd*8];
#pragma unroll
      for (int nt = 0; nt < 2; nt++)
        bfr[nt] = *(const bf16x8*)&Bs[wc*32 + nt*16 + ln][c*32 + qd*8];
#pragma unroll
      for (int mt = 0; mt < 4; mt++)
#pragma unroll
        for (int nt = 0; nt < 2; nt++)
          acc[mt][nt] = __builtin_amdgcn_mfma_f32_16x16x32_bf16(af[mt], bfr[nt], acc[mt][nt], 0, 0, 0);
    }
  }
#pragma unroll
  for (int mt = 0; mt < 4; mt++)
#pragma unroll
    for (int nt = 0; nt < 2; nt++)
#pragma unroll
      for (int r = 0; r < 4; r++) {
        int gm = m0 + wr*64 + mt*16 + qd*4 + r;
        int gn = n0 + wc*32 + nt*16 + ln;
        float v = acc[mt][nt][r];
        if (bias)  v += bias[gn];
        if (resid) v += resid[(size_t)gm*N + gn];
        if (OUT_BF16) sto(v, &((bf16_t*)Cout)[(size_t)gm*N + gn]);
        else          sto(v, &((float*)Cout)[(size_t)gm*N + gn]);
      }
}

// =========================== 3-term bf16 MFMA GEMM (fp32 emulation): C = (Ah+Al)(Bh+Bl)^T ===========================
__global__ __launch_bounds__(256) void gemm3_kernel(
    const bf16_t* __restrict__ Ah, const bf16_t* __restrict__ Al,
    const bf16_t* __restrict__ Bth, const bf16_t* __restrict__ Btl,
    float* __restrict__ C, int M, int N, int K)
{
  __shared__ bf16_t Ash[128][72];
  __shared__ bf16_t Asl[128][72];
  __shared__ bf16_t Bsh[64][72];
  __shared__ bf16_t Bsl[64][72];
  const int tid = threadIdx.x;
  const int m0 = blockIdx.x * 128, n0 = blockIdx.y * 64;
  const int w = tid >> 6, lane = tid & 63;
  const int wr = w >> 1, wc = w & 1;
  const int ln = lane & 15, qd = lane >> 4;
  f32x4 zero = {0.f, 0.f, 0.f, 0.f};
  f32x4 acc[4][2];
#pragma unroll
  for (int a = 0; a < 4; a++)
#pragma unroll
    for (int b = 0; b < 2; b++) acc[a][b] = zero;

  for (int k0 = 0; k0 < K; k0 += 64) {
    __syncthreads();
#pragma unroll
    for (int i = 0; i < 4; i++) {
      int vid = tid + i*256;
      int r = vid >> 3, c8 = (vid & 7) * 8;
      *(bf16x8*)&Ash[r][c8] = *(const bf16x8*)(Ah + (size_t)(m0+r)*K + k0 + c8);
      *(bf16x8*)&Asl[r][c8] = *(const bf16x8*)(Al + (size_t)(m0+r)*K + k0 + c8);
    }
#pragma unroll
    for (int i = 0; i < 2; i++) {
      int vid = tid + i*256;
      int r = vid >> 3, c8 = (vid & 7) * 8;
      *(bf16x8*)&Bsh[r][c8] = *(const bf16x8*)(Bth + (size_t)(n0+r)*K + k0 + c8);
      *(bf16x8*)&Bsl[r][c8] = *(const bf16x8*)(Btl + (size_t)(n0+r)*K + k0 + c8);
    }
    __syncthreads();
#pragma unroll
    for (int c = 0; c < 2; c++) {
      bf16x8 afh[4], afl[4], bfh[2], bfl[2];
#pragma unroll
      for (int mt = 0; mt < 4; mt++) {
        afh[mt] = *(const bf16x8*)&Ash[wr*64 + mt*16 + ln][c*32 + qd*8];
        afl[mt] = *(const bf16x8*)&Asl[wr*64 + mt*16 + ln][c*32 + qd*8];
      }
#pragma unroll
      for (int nt = 0; nt < 2; nt++) {
        bfh[nt] = *(const bf16x8*)&Bsh[wc*32 + nt*16 + ln][c*32 + qd*8];
        bfl[nt] = *(const bf16x8*)&Bsl[wc*32 + nt*16 + ln][c*32 + qd*8];
      }
#pragma unroll
      for (int mt = 0; mt < 4; mt++)
#pragma unroll
        for (int nt = 0; nt < 2; nt++) {
          acc[mt][nt] = __builtin_amdgcn_mfma_f32_16x16x32_bf16(afh[mt], bfl[nt], acc[mt][nt], 0, 0, 0);
          acc[mt][nt] = __builtin_amdgcn_mfma_f32_16x16x32_bf16(afl[mt], bfh[nt], acc[mt][nt], 0, 0, 0);
          acc[mt][nt] = __builtin_amdgcn_mfma_f32_16x16x32_bf16(afh[mt], bfh[nt], acc[mt][nt], 0, 0, 0);
        }
    }
  }
#pragma unroll
  for (int mt = 0; mt < 4; mt++)
#pragma unroll
    for (int nt = 0; nt < 2; nt++)
#pragma unroll
      for (int r = 0; r < 4; r++) {
        int gm = m0 + wr*64 + mt*16 + qd*4 + r;
        int gn = n0 + wc*32 + nt*16 + ln;
        C[(size_t)gm*N + gn] = acc[mt][nt][r];
      }
}

// =========================== GEGLU ===========================
__global__ __launch_bounds__(256) void geglu_kernel(
    const bf16_t* __restrict__ proj, bf16_t* __restrict__ gg)
{
  int idx = blockIdx.x * 256 + threadIdx.x;
  int m = idx / 320, c4 = (idx - m*320) * 4;
  bf16x4 a = *(const bf16x4*)(proj + (size_t)m*2560 + c4);
  bf16x4 g = *(const bf16x4*)(proj + (size_t)m*2560 + 1280 + c4);
  bf16x4 r;
#pragma unroll
  for (int i = 0; i < 4; i++) {
    float gf = b2f(g[i]);
    float ge = 0.5f * gf * (1.f + erff(gf * 0.70710678118654752f));
    r[i] = f2b(b2f(a[i]) * ge);
  }
  *(bf16x4*)(gg + (size_t)m*1280 + c4) = r;
}

// =========================== launch ===========================
extern "C" void kernel_launch(void* const* d_in, const int* in_sizes, int n_in,
                              void* d_out, int out_size, void* d_ws, size_t ws_size,
                              hipStream_t stream)
{
  const float* x    = (const float*)d_in[0];
  const float* ctx  = (const float*)d_in[1];
  const float* fam  = (const float*)d_in[2];
  const float* g1   = (const float*)d_in[3];
  const float* b1   = (const float*)d_in[4];
  const float* g2   = (const float*)d_in[5];
  const float* b2   = (const float*)d_in[6];
  const float* g3   = (const float*)d_in[7];
  const float* b3   = (const float*)d_in[8];
  const float* Wq1  = (const float*)d_in[9];
  const float* Wk1  = (const float*)d_in[10];
  const float* Wv1  = (const float*)d_in[11];
  const float* Wo1  = (const float*)d_in[12];
  const float* bo1  = (const float*)d_in[13];
  const float* Wq2  = (const float*)d_in[14];
  const float* Wk2  = (const float*)d_in[15];
  const float* Wv2  = (const float*)d_in[16];
  const float* Wo2  = (const float*)d_in[17];
  const float* bo2  = (const float*)d_in[18];
  const float* Wff1 = (const float*)d_in[19];
  const float* bff1 = (const float*)d_in[20];
  const float* Wff2 = (const float*)d_in[21];
  const float* bff2 = (const float*)d_in[22];
  const int*   ufca = (const int*)d_in[23];

  char* ws = (char*)d_ws;
  bf16_t* qkvb = (bf16_t*)(ws + 0);          //  7,864,320  bf16 [4096][960]
  bf16_t* vtg  = (bf16_t*)(ws + 7864320);    //  2,621,440  bf16 [8][40][4096]
  bf16_t* o1a  = (bf16_t*)(ws + 10485760);   //  2,621,440  bf16 [4096][320]
  bf16_t* h1b  = (bf16_t*)(ws + 13107200);   //  2,621,440  bf16 [4096][320]
  bf16_t* h2hi = (bf16_t*)(ws + 15728640);   //  2,621,440  bf16 [4096][320]
  bf16_t* h2lo = (bf16_t*)(ws + 18350080);   //  2,621,440  bf16 [4096][320]
  float*  x2   = (float*)(ws + 20971520);    //  5,242,880  f32  [4096][320]
  float*  q2   = (float*)(ws + 26214400);    //  5,242,880  f32  [4096][320]
  float*  kv2  = (float*)(ws + 31457280);    //    197,120  f32  [77][640]
  bf16_t* o2   = (bf16_t*)(ws + 31654400);   //  2,621,440  bf16 [4096][320]
  float*  x3   = (float*)(ws + 34275840);    //  5,242,880  f32  [4096][320]
  bf16_t* h3b  = (bf16_t*)(ws + 39518720);   //  2,621,440  bf16 [4096][320]
  bf16_t* wqkvt = (bf16_t*)(ws + 42140160);  //    614,400
  bf16_t* wo1t  = (bf16_t*)(ws + 42754560);  //    204,800
  float*  wkv2t = (float*)(ws + 42959360);   //  1,966,080  f32 [640][768]
  bf16_t* wo2t  = (bf16_t*)(ws + 44925440);  //    204,800
  bf16_t* wff1t = (bf16_t*)(ws + 45130240);  //  1,638,400
  bf16_t* wff2t = (bf16_t*)(ws + 46768640);  //    819,200
  float*  lpart = (float*)(ws + 47587840);   //    262,144  f32 [2][8][4096]
  bf16_t* wq2th = (bf16_t*)(ws + 47849984);  //    204,800
  bf16_t* wq2tl = (bf16_t*)(ws + 48054784);  //    204,800  -> end 48,259,584
  // opart overlaps x2..~h3b (dead during flash+merge): f32 [2][8][4096][40]
  float*  opart = (float*)(ws + 20971520);
  bf16_t* proj = (bf16_t*)(ws + 0);          // bf16 [4096][2560] (FF phase only)
  bf16_t* gg   = (bf16_t*)(ws + 20971520);   // bf16 [4096][1280] (FF phase only)

  float* xout = (float*)d_out;

  prep_kernel<<<1024, 256, 0, stream>>>(Wq1, Wk1, Wv1, Wo1, Wq2, Wk2, Wv2, Wo2, Wff1, Wff2,
                                        wqkvt, wo1t, wkv2t, wo2t, wff1t, wff2t, wq2th, wq2tl);
  // --- attn1 (bf16 MFMA flash) ---
  ln_kernel<bf16_t><<<1024, 256, 0, stream>>>(x, g1, b1, h1b);
  gemm_bf16_kernel<1><<<dim3(32,15), 256, 0, stream>>>(h1b, wqkvt, nullptr, nullptr, qkvb, 4096, 960, 320);
  repack_vt_kernel<<<dim3(64,8), 256, 0, stream>>>(qkvb, vtg);
  flash_self_kernel<<<dim3(64,8,2), 256, 0, stream>>>(qkvb, vtg, opart, lpart);
  merge_o1_kernel<<<5120, 256, 0, stream>>>(opart, lpart, o1a);
  gemm_bf16_kernel<0><<<dim3(32,5), 256, 0, stream>>>(o1a, wo1t, bo1, x, x2, 4096, 320, 320);
  // --- attn2 (sim2 path: fp32-emulated q2 GEMM + exact fp32 kv2) ---
  ln2_split_kernel<<<1024, 256, 0, stream>>>(x2, g2, b2, h2hi, h2lo);
  gemm3_kernel<<<dim3(32,5), 256, 0, stream>>>(h2hi, h2lo, wq2th, wq2tl, q2, 4096, 320, 320);
  kv2_dot_kernel<<<3080, 256, 0, stream>>>(ctx, wkv2t, kv2);
  attn_cross_kernel<<<dim3(128,8), 256, 0, stream>>>(q2, kv2, fam, ufca, o2);
  gemm_bf16_kernel<0><<<dim3(32,5), 256, 0, stream>>>(o2, wo2t, bo2, x2, x3, 4096, 320, 320);
  // --- GEGLU FF ---
  ln_kernel<bf16_t><<<1024, 256, 0, stream>>>(x3, g3, b3, h3b);
  gemm_bf16_kernel<1><<<dim3(32,40), 256, 0, stream>>>(h3b, wff1t, bff1, nullptr, proj, 4096, 2560, 320);
  geglu_kernel<<<5120, 256, 0, stream>>>(proj, gg);
  gemm_bf16_kernel<0><<<dim3(32,5), 256, 0, stream>>>(gg, wff2t, bff2, x3, xout, 4096, 320, 1280);
}

// Round 5
// 346.964 us; speedup vs baseline: 5.2616x; 1.1864x over previous
//
#include <hip/hip_runtime.h>
#include <math.h>

typedef __bf16 bf16_t;
typedef __bf16 bf16x8 __attribute__((ext_vector_type(8)));
typedef __bf16 bf16x4 __attribute__((ext_vector_type(4)));
typedef float  f32x4  __attribute__((ext_vector_type(4)));
typedef short  s16x4  __attribute__((ext_vector_type(4)));

static constexpr float ATT_SCALE = 0.15811388300841897f; // 40^-0.5
static constexpr float SC2 = 0.22811031f;                // ATT_SCALE * log2(e)
static constexpr float LOG2E = 1.4426950408889634f;

__device__ __forceinline__ bf16_t f2b(float f) {
  unsigned u = __float_as_uint(f);
  u = (u + 0x7fffu + ((u >> 16) & 1u)) >> 16;   // RNE
  unsigned short s = (unsigned short)u;
  bf16_t r;
  *(unsigned short*)&r = s;
  return r;
}
__device__ __forceinline__ float b2f(bf16_t b) {
  unsigned short s = *(const unsigned short*)&b;
  return __uint_as_float(((unsigned)s) << 16);
}
__device__ __forceinline__ void sto(float v, float* p)  { *p = v; }
__device__ __forceinline__ void sto(float v, bf16_t* p) { *p = f2b(v); }
__device__ __forceinline__ unsigned pk2(float a, float b) {
  unsigned ua = (__float_as_uint(a) + 0x8000u) >> 16;
  unsigned ub = (__float_as_uint(b) + 0x8000u) & 0xffff0000u;
  return ua | ub;
}

// =========================== weight repack ===========================
// wqkvt bf16 [960][320]; wo1t bf16 [320][320]; wkv2t f32 [640][768];
// wo2t bf16 [320][320]; wff1t bf16 [2560][320]; wff2t bf16 [320][1280];
// wq2t hi/lo bf16 [320][320]; famh/faml bf16 [96][96] (zero-padded hi/lo split of fam).
__global__ __launch_bounds__(256) void prep_kernel(
    const float* __restrict__ Wq1, const float* __restrict__ Wk1, const float* __restrict__ Wv1,
    const float* __restrict__ Wo1, const float* __restrict__ Wq2,
    const float* __restrict__ Wk2, const float* __restrict__ Wv2, const float* __restrict__ Wo2,
    const float* __restrict__ Wff1, const float* __restrict__ Wff2,
    const float* __restrict__ fam,
    bf16_t* __restrict__ wqkvt, bf16_t* __restrict__ wo1t, float* __restrict__ wkv2t,
    bf16_t* __restrict__ wo2t, bf16_t* __restrict__ wff1t, bf16_t* __restrict__ wff2t,
    bf16_t* __restrict__ wq2th, bf16_t* __restrict__ wq2tl,
    bf16_t* __restrict__ famh, bf16_t* __restrict__ faml)
{
  const int T1 = 960*320;
  const int T2 = T1 + 320*320;
  const int T3 = T2 + 768*640;
  const int T4 = T3 + 320*320;
  const int T5 = T4 + 2560*320;
  const int T6 = T5 + 320*1280;
  const int T7 = T6 + 320*320;
  const int T8 = T7 + 96*96;
  for (int i = blockIdx.x*256 + threadIdx.x; i < T8; i += gridDim.x*256) {
    if (i < T1) {
      int n = i / 320, k = i - n*320;
      float v = (n < 320) ? Wq1[k*320+n] : (n < 640) ? Wk1[k*320+n-320] : Wv1[k*320+n-640];
      wqkvt[i] = f2b(v);
    } else if (i < T2) {
      int e = i - T1; int n = e / 320, k = e - n*320;
      wo1t[e] = f2b(Wo1[k*320+n]);
    } else if (i < T3) {
      int e = i - T2; int n = e / 768, k = e - n*768;
      wkv2t[e] = (n < 320) ? Wk2[k*320+n] : Wv2[k*320+n-320];
    } else if (i < T4) {
      int e = i - T3; int n = e / 320, k = e - n*320;
      wo2t[e] = f2b(Wo2[k*320+n]);
    } else if (i < T5) {
      int e = i - T4; int n = e / 320, k = e - n*320;
      wff1t[e] = f2b(Wff1[(size_t)k*2560+n]);
    } else if (i < T6) {
      int e = i - T5; int n = e / 1280, k = e - n*1280;
      wff2t[e] = f2b(Wff2[k*320+n]);
    } else if (i < T7) {
      int e = i - T6; int n = e / 320, k = e - n*320;
      float v = Wq2[k*320+n];
      bf16_t h = f2b(v);
      wq2th[e] = h;
      wq2tl[e] = f2b(v - b2f(h));
    } else {
      int e = i - T7; int d = e / 96, k = e - d*96;
      float v = (d < 77 && k < 77) ? fam[d*77 + k] : 0.f;
      bf16_t h = f2b(v);
      famh[e] = h;
      faml[e] = f2b(v - b2f(h));
    }
  }
}

// =========================== LayerNorm ===========================
template<typename OT>
__global__ __launch_bounds__(256) void ln_kernel(
    const float* __restrict__ x, const float* __restrict__ g, const float* __restrict__ b,
    OT* __restrict__ out)
{
  const int lane = threadIdx.x & 63;
  const int row = blockIdx.x * 4 + (threadIdx.x >> 6);
  const float* xr = x + (size_t)row * 320;
  float v[5], s = 0.f, s2 = 0.f;
#pragma unroll
  for (int i = 0; i < 5; i++) { v[i] = xr[lane + i*64]; s += v[i]; s2 += v[i]*v[i]; }
#pragma unroll
  for (int o = 32; o; o >>= 1) { s += __shfl_xor(s, o); s2 += __shfl_xor(s2, o); }
  float mu = s * (1.f/320.f);
  float rs = rsqrtf(fmaxf(s2*(1.f/320.f) - mu*mu, 0.f) + 1e-5f);
#pragma unroll
  for (int i = 0; i < 5; i++) {
    int c = lane + i*64;
    sto((v[i]-mu)*rs*g[c] + b[c], &out[(size_t)row*320 + c]);
  }
}

// LayerNorm writing hi/lo bf16 split
__global__ __launch_bounds__(256) void ln2_split_kernel(
    const float* __restrict__ x, const float* __restrict__ g, const float* __restrict__ b,
    bf16_t* __restrict__ hi, bf16_t* __restrict__ lo)
{
  const int lane = threadIdx.x & 63;
  const int row = blockIdx.x * 4 + (threadIdx.x >> 6);
  const float* xr = x + (size_t)row * 320;
  float v[5], s = 0.f, s2 = 0.f;
#pragma unroll
  for (int i = 0; i < 5; i++) { v[i] = xr[lane + i*64]; s += v[i]; s2 += v[i]*v[i]; }
#pragma unroll
  for (int o = 32; o; o >>= 1) { s += __shfl_xor(s, o); s2 += __shfl_xor(s2, o); }
  float mu = s * (1.f/320.f);
  float rs = rsqrtf(fmaxf(s2*(1.f/320.f) - mu*mu, 0.f) + 1e-5f);
#pragma unroll
  for (int i = 0; i < 5; i++) {
    int c = lane + i*64;
    float y = (v[i]-mu)*rs*g[c] + b[c];
    bf16_t h = f2b(y);
    hi[(size_t)row*320 + c] = h;
    lo[(size_t)row*320 + c] = f2b(y - b2f(h));
  }
}

// =========================== kv2 dot-product GEMM ===========================
__global__ __launch_bounds__(256) void kv2_dot_kernel(
    const float* __restrict__ ctx, const float* __restrict__ wkv2t, float* __restrict__ kv2)
{
  const int gid = blockIdx.x*16 + (threadIdx.x >> 4);
  const int q = threadIdx.x & 15;
  const int m = gid / 640, n = gid - m*640;
  const float4* a = (const float4*)(ctx + (size_t)m*768);
  const float4* b = (const float4*)(wkv2t + (size_t)n*768);
  float acc = 0.f;
#pragma unroll
  for (int i = 0; i < 12; i++) {
    float4 av = a[i*16+q], bv = b[i*16+q];
    acc += av.x*bv.x + av.y*bv.y + av.z*bv.z + av.w*bv.w;
  }
#pragma unroll
  for (int o = 8; o; o >>= 1) acc += __shfl_xor(acc, o);
  if (q == 0) kv2[(size_t)m*640 + n] = acc;
}

// =========================== kv2 post: build MFMA-friendly K2 hi/lo and V^T ===========================
// k2h/k2l bf16 [8][96 j][64 d] (zero-padded); v2t bf16 [8][48 d][96 j] (zero-padded)
__global__ __launch_bounds__(256) void kv2_post_kernel(
    const float* __restrict__ kv2, bf16_t* __restrict__ k2h, bf16_t* __restrict__ k2l,
    bf16_t* __restrict__ v2t)
{
  const int NK = 8*96*64;
  const int NV = 8*48*96;
  int i = blockIdx.x*256 + threadIdx.x;
  if (i < NK) {
    int h = i / (96*64), r = i - h*96*64, j = r >> 6, d = r & 63;
    float v = (j < 77 && d < 40) ? kv2[(size_t)j*640 + h*40 + d] : 0.f;
    bf16_t hh = f2b(v);
    k2h[i] = hh;
    k2l[i] = f2b(v - b2f(hh));
  } else if (i < NK + NV) {
    int e = i - NK;
    int h = e / (48*96), r = e - h*48*96, d = r / 96, j = r - d*96;
    v2t[e] = f2b((d < 40 && j < 77) ? kv2[(size_t)j*640 + 320 + h*40 + d] : 0.f);
  }
}

// =========================== V^T repack (self-attn) ===========================
__global__ __launch_bounds__(256) void repack_vt_kernel(
    const bf16_t* __restrict__ qkvb, bf16_t* __restrict__ vtg)
{
  __shared__ bf16_t T[64*44];
  const int tid = threadIdx.x;
  const int t0 = blockIdx.x * 64, h = blockIdx.y;
  for (int e = tid; e < 320; e += 256) {
    int t = e / 5, c8 = (e - t*5) * 8;
    *(bf16x8*)&T[t*44 + c8] = *(const bf16x8*)(qkvb + (size_t)(t0+t)*960 + 640 + h*40 + c8);
  }
  __syncthreads();
  for (int e = tid; e < 320; e += 256) {
    int d = e >> 3, t8 = (e & 7) * 8;
    bf16x8 v;
#pragma unroll
    for (int j = 0; j < 8; j++) v[j] = T[(t8+j)*44 + d];
    *(bf16x8*)&vtg[((size_t)h*40 + d)*4096 + t0 + t8] = v;
  }
}

// =========================== bf16 MFMA flash self-attention ===========================
__global__ __launch_bounds__(256, 4) void flash_self_kernel(
    const bf16_t* __restrict__ qkvb, const bf16_t* __restrict__ vtg,
    float* __restrict__ opart, float* __restrict__ lpart)
{
  __shared__ float Red[6144];
  __shared__ float Lred[4][64];
  const int tid = threadIdx.x;
  const int w = tid >> 6, lane = tid & 63;
  const int ln = lane & 15, qd = lane >> 4;
  const int h = blockIdx.y;
  const int q0 = blockIdx.x * 64;
  const int split = blockIdx.z;

  bf16x8 zero8 = {};
  bf16x8 bq[4][2];
#pragma unroll
  for (int nt = 0; nt < 4; nt++) {
    const bf16_t* qp = qkvb + (size_t)(q0 + nt*16 + ln)*960 + h*40;
    bq[nt][0] = *(const bf16x8*)(qp + qd*8);
    bq[nt][1] = (qd == 0) ? *(const bf16x8*)(qp + 32) : zero8;
  }

  f32x4 zero4 = {0.f,0.f,0.f,0.f};
  f32x4 oacc[3][4];
#pragma unroll
  for (int a = 0; a < 3; a++)
#pragma unroll
    for (int b = 0; b < 4; b++) oacc[a][b] = zero4;
  float l_acc[4] = {0.f,0.f,0.f,0.f};

  const bf16_t* kbase = qkvb + 320 + h*40;
  const bf16_t* vbase = vtg + (size_t)h*40*4096;

  for (int kt = 0; kt < 32; kt++) {
    int k0 = split*2048 + kt*64;
    int krow = k0 + w*16 + ln;
    const bf16_t* kp = kbase + (size_t)krow*960;
    bf16x8 ka0 = *(const bf16x8*)(kp + qd*8);
    bf16x8 ka1 = (qd == 0) ? *(const bf16x8*)(kp + 32) : zero8;

    uint2 ppk[4];
#pragma unroll
    for (int nt = 0; nt < 4; nt++) {
      f32x4 s = __builtin_amdgcn_mfma_f32_16x16x32_bf16(ka0, bq[nt][0], zero4, 0, 0, 0);
      s = __builtin_amdgcn_mfma_f32_16x16x32_bf16(ka1, bq[nt][1], s, 0, 0, 0);
      float p0 = __builtin_amdgcn_exp2f(s[0]*SC2);
      float p1 = __builtin_amdgcn_exp2f(s[1]*SC2);
      float p2 = __builtin_amdgcn_exp2f(s[2]*SC2);
      float p3 = __builtin_amdgcn_exp2f(s[3]*SC2);
      l_acc[nt] += (p0+p1)+(p2+p3);
      ppk[nt].x = pk2(p0, p1);
      ppk[nt].y = pk2(p2, p3);
    }
#pragma unroll
    for (int dt = 0; dt < 3; dt++) {
      const bf16_t* vp = vbase + (size_t)(dt*16+ln)*4096 + k0 + w*16 + qd*4;
      s16x4 va = *(const s16x4*)vp;
#pragma unroll
      for (int nt = 0; nt < 4; nt++) {
        s16x4 pb = *(const s16x4*)&ppk[nt];
        oacc[dt][nt] = __builtin_amdgcn_mfma_f32_16x16x16bf16_1k(va, pb, oacc[dt][nt], 0, 0, 0);
      }
    }
  }

#pragma unroll
  for (int nt = 0; nt < 4; nt++) {
    l_acc[nt] += __shfl_xor(l_acc[nt], 16);
    l_acc[nt] += __shfl_xor(l_acc[nt], 32);
  }
  if (qd == 0) {
#pragma unroll
    for (int nt = 0; nt < 4; nt++) Lred[w][nt*16 + ln] = l_acc[nt];
  }
  __syncthreads();
  if (tid < 64) {
    float lt = Lred[0][tid] + Lred[1][tid] + Lred[2][tid] + Lred[3][tid];
    lpart[(size_t)(split*8 + h)*4096 + q0 + tid] = lt;
  }
  float* obase = opart + ((size_t)(split*8 + h)*4096 + q0)*40;
  for (int np = 0; np < 2; np++) {
    __syncthreads();
#pragma unroll
    for (int e = 0; e < 2; e++) {
      int nt = np*2 + e;
#pragma unroll
      for (int dt = 0; dt < 3; dt++)
        *(f32x4*)&Red[(((w*2+e)*3 + dt)*16 + ln)*16 + qd*4] = oacc[dt][nt];
    }
    __syncthreads();
    int e = tid >> 7;
    int lq = (tid >> 3) & 15;
    int dbase = tid & 7;
#pragma unroll
    for (int i = 0; i < 5; i++) {
      int d = dbase + i*8;
      int dt = d >> 4, drow = d & 15;
      float v = Red[((0*2+e)*3 + dt)*256 + lq*16 + drow]
              + Red[((1*2+e)*3 + dt)*256 + lq*16 + drow]
              + Red[((2*2+e)*3 + dt)*256 + lq*16 + drow]
              + Red[((3*2+e)*3 + dt)*256 + lq*16 + drow];
      obase[(size_t)((np*2+e)*16 + lq)*40 + d] = v;
    }
  }
}

// =========================== merge K-split partials ===========================
__global__ __launch_bounds__(256) void merge_o1_kernel(
    const float* __restrict__ op, const float* __restrict__ lp, bf16_t* __restrict__ o1a)
{
  int i = blockIdx.x*256 + threadIdx.x;
  int q = i / 320, c = i - q*320;
  int h = c / 40, d = c - h*40;
  size_t base = ((size_t)h*4096 + q)*40 + d;
  float l = lp[h*4096 + q] + lp[32768 + h*4096 + q];
  float o = op[base] + op[base + 1310720];
  o1a[i] = f2b(o / l);
}

// =========================== cross-attention (all-MFMA, single-pass, no barriers) ===========================
// wave = 16 q-rows x 1 head. SIM = Q K^T (3-term fp32-emulated bf16 MFMA);
// FW = SIM fam^T (3-term, SIM via wave-private LDS C->A transform);
// mask/exp/row-reduce in C-regs; O = P V^T (bf16 MFMA). grid (64, 8), block 256 (4 indep waves).
__global__ __launch_bounds__(256) void attn_cross_kernel(
    const float* __restrict__ q2, const bf16_t* __restrict__ k2h, const bf16_t* __restrict__ k2l,
    const bf16_t* __restrict__ famh, const bf16_t* __restrict__ faml,
    const bf16_t* __restrict__ v2t, const int* __restrict__ use_fca,
    bf16_t* __restrict__ o2)
{
  __shared__ bf16_t SMh[4][16*96];
  __shared__ bf16_t SMl[4][16*96];
  __shared__ bf16_t PAs[4][16*96];
  const int tid = threadIdx.x;
  const int w = tid >> 6, lane = tid & 63;
  const int ln = lane & 15, qd = lane >> 4;
  const int h = blockIdx.y;
  const int q0 = blockIdx.x*64 + w*16;
  const int fca = use_fca[0];
  bf16_t* smh = SMh[w];
  bf16_t* sml = SMl[w];
  bf16_t* pa  = PAs[w];

  // zero pad cols 80..95 of the wave-private LDS tiles
  {
    bf16x4 z = {};
    int q = lane >> 2, c = 80 + (lane & 3)*4;
    *(bf16x4*)&smh[q*96 + c] = z;
    *(bf16x4*)&sml[q*96 + c] = z;
    *(bf16x4*)&pa [q*96 + c] = z;
  }

  // ---- Q A-frags (hi/lo split on the fly) ----
  bf16x8 zero8 = {};
  bf16x8 aqh0, aql0, aqh1 = zero8, aql1 = zero8;
  {
    const float* qp = q2 + (size_t)(q0 + ln)*320 + h*40;
    float4 v0 = *(const float4*)(qp + qd*8);
    float4 v1 = *(const float4*)(qp + qd*8 + 4);
    float qv[8] = {v0.x,v0.y,v0.z,v0.w,v1.x,v1.y,v1.z,v1.w};
#pragma unroll
    for (int i = 0; i < 8; i++) {
      bf16_t hh = f2b(qv[i]);
      aqh0[i] = hh; aql0[i] = f2b(qv[i] - b2f(hh));
    }
    if (qd == 0) {
      float4 u0 = *(const float4*)(qp + 32);
      float4 u1 = *(const float4*)(qp + 36);
      float uv[8] = {u0.x,u0.y,u0.z,u0.w,u1.x,u1.y,u1.z,u1.w};
#pragma unroll
      for (int i = 0; i < 8; i++) {
        bf16_t hh = f2b(uv[i]);
        aqh1[i] = hh; aql1[i] = f2b(uv[i] - b2f(hh));
      }
    }
  }

  // ---- SIM = Q K^T (5 n-tiles of 16 keys) ----
  f32x4 zero4 = {0.f,0.f,0.f,0.f};
  float ss[5][4];
#pragma unroll
  for (int nt = 0; nt < 5; nt++) {
    const bf16_t* kb = k2h + ((size_t)h*96 + nt*16 + ln)*64 + qd*8;
    const bf16_t* kl = k2l + ((size_t)h*96 + nt*16 + ln)*64 + qd*8;
    bf16x8 kh0 = *(const bf16x8*)kb;
    bf16x8 kh1 = *(const bf16x8*)(kb + 32);
    bf16x8 kl0 = *(const bf16x8*)kl;
    bf16x8 kl1 = *(const bf16x8*)(kl + 32);
    f32x4 s;
    s = __builtin_amdgcn_mfma_f32_16x16x32_bf16(aqh0, kl0, zero4, 0, 0, 0);
    s = __builtin_amdgcn_mfma_f32_16x16x32_bf16(aql0, kh0, s, 0, 0, 0);
    s = __builtin_amdgcn_mfma_f32_16x16x32_bf16(aqh0, kh0, s, 0, 0, 0);
    s = __builtin_amdgcn_mfma_f32_16x16x32_bf16(aqh1, kl1, s, 0, 0, 0);
    s = __builtin_amdgcn_mfma_f32_16x16x32_bf16(aql1, kh1, s, 0, 0, 0);
    s = __builtin_amdgcn_mfma_f32_16x16x32_bf16(aqh1, kh1, s, 0, 0, 0);
    // scale + write hi/lo to wave-private LDS (C->A transform), keep scaled copy
#pragma unroll
    for (int r = 0; r < 4; r++) {
      float sv = s[r] * ATT_SCALE;
      ss[nt][r] = sv;
      bf16_t hh = f2b(sv);
      smh[(qd*4 + r)*96 + nt*16 + ln] = hh;
      sml[(qd*4 + r)*96 + nt*16 + ln] = f2b(sv - b2f(hh));
    }
  }

  // ---- FW = SIM fam^T (3-term) ----
  f32x4 facc[5];
#pragma unroll
  for (int nt = 0; nt < 5; nt++) facc[nt] = zero4;
#pragma unroll
  for (int c = 0; c < 3; c++) {
    bf16x8 sah = *(const bf16x8*)&smh[ln*96 + c*32 + qd*8];
    bf16x8 sal = *(const bf16x8*)&sml[ln*96 + c*32 + qd*8];
#pragma unroll
    for (int nt = 0; nt < 5; nt++) {
      const bf16_t* fb = famh + ((size_t)(nt*16 + ln))*96 + c*32 + qd*8;
      const bf16_t* fl = faml + ((size_t)(nt*16 + ln))*96 + c*32 + qd*8;
      bf16x8 fh8 = *(const bf16x8*)fb;
      bf16x8 fl8 = *(const bf16x8*)fl;
      facc[nt] = __builtin_amdgcn_mfma_f32_16x16x32_bf16(sah, fl8, facc[nt], 0, 0, 0);
      facc[nt] = __builtin_amdgcn_mfma_f32_16x16x32_bf16(sal, fh8, facc[nt], 0, 0, 0);
      facc[nt] = __builtin_amdgcn_mfma_f32_16x16x32_bf16(sah, fh8, facc[nt], 0, 0, 0);
    }
  }

  // ---- mask + exp + row-sum (C-layout: row q = qd*4+r, col = nt*16+ln) ----
  float pr[5][4];
  if (fca) {
    float fwv[5][4], fm[4];
#pragma unroll
    for (int nt = 0; nt < 5; nt++)
#pragma unroll
      for (int r = 0; r < 4; r++) fwv[nt][r] = fminf(fabsf(facc[nt][r]), 1.f);
#pragma unroll
    for (int r = 0; r < 4; r++) {
      float m = fmaxf(fmaxf(fwv[0][r], fwv[1][r]), fmaxf(fwv[2][r], fmaxf(fwv[3][r], fwv[4][r])));
#pragma unroll
      for (int o = 8; o; o >>= 1) m = fmaxf(m, __shfl_xor(m, o));
      fm[r] = m;
    }
#pragma unroll
    for (int nt = 0; nt < 5; nt++)
#pragma unroll
      for (int r = 0; r < 4; r++) {
        float lg = ss[nt][r] - ((fwv[nt][r] > 0.6f*(fm[r] + 1e-6f)) ? 0.f : 50.f);
        pr[nt][r] = __builtin_amdgcn_exp2f(lg * LOG2E);
      }
  } else {
#pragma unroll
    for (int nt = 0; nt < 5; nt++)
#pragma unroll
      for (int r = 0; r < 4; r++)
        pr[nt][r] = __builtin_amdgcn_exp2f(ss[nt][r] * LOG2E);
  }
  // zero the key-padding columns (cols 77..79 live in nt=4, ln>=13)
  if (ln >= 13) {
#pragma unroll
    for (int r = 0; r < 4; r++) pr[4][r] = 0.f;
  }
  float l_[4] = {0.f,0.f,0.f,0.f};
#pragma unroll
  for (int nt = 0; nt < 5; nt++)
#pragma unroll
    for (int r = 0; r < 4; r++) {
      l_[r] += pr[nt][r];
      pa[(qd*4 + r)*96 + nt*16 + ln] = f2b(pr[nt][r]);
    }
#pragma unroll
  for (int r = 0; r < 4; r++)
#pragma unroll
    for (int o = 8; o; o >>= 1) l_[r] += __shfl_xor(l_[r], o);

  // ---- O = P V^T ----
  f32x4 oacc[3];
#pragma unroll
  for (int nt = 0; nt < 3; nt++) oacc[nt] = zero4;
#pragma unroll
  for (int c = 0; c < 3; c++) {
    bf16x8 paf = *(const bf16x8*)&pa[ln*96 + c*32 + qd*8];
#pragma unroll
    for (int nt = 0; nt < 3; nt++) {
      bf16x8 vb = *(const bf16x8*)(v2t + ((size_t)h*48 + nt*16 + ln)*96 + c*32 + qd*8);
      oacc[nt] = __builtin_amdgcn_mfma_f32_16x16x32_bf16(paf, vb, oacc[nt], 0, 0, 0);
    }
  }
  float inv[4];
#pragma unroll
  for (int r = 0; r < 4; r++) inv[r] = 1.f / l_[r];
#pragma unroll
  for (int nt = 0; nt < 3; nt++) {
    int d = nt*16 + ln;
    if (d < 40) {
#pragma unroll
      for (int r = 0; r < 4; r++)
        o2[(size_t)(q0 + qd*4 + r)*320 + h*40 + d] = f2b(oacc[nt][r]*inv[r]);
    }
  }
}

// =========================== bf16 MFMA GEMM: C = A[M][K] @ Bt[N][K]^T ===========================
template<int OUT_BF16>
__global__ __launch_bounds__(256) void gemm_bf16_kernel(
    const bf16_t* __restrict__ A, const bf16_t* __restrict__ Bt,
    const float* __restrict__ bias, const float* __restrict__ resid,
    void* __restrict__ Cout, int M, int N, int K)
{
  __shared__ bf16_t As[128][72];
  __shared__ bf16_t Bs[64][72];
  const int tid = threadIdx.x;
  const int m0 = blockIdx.x * 128, n0 = blockIdx.y * 64;
  const int w = tid >> 6, lane = tid & 63;
  const int wr = w >> 1, wc = w & 1;
  const int ln = lane & 15, qd = lane >> 4;
  f32x4 zero = {0.f, 0.f, 0.f, 0.f};
  f32x4 acc[4][2];
#pragma unroll
  for (int a = 0; a < 4; a++)
#pragma unroll
    for (int b = 0; b < 2; b++) acc[a][b] = zero;

  for (int k0 = 0; k0 < K; k0 += 64) {
    __syncthreads();
#pragma unroll
    for (int i = 0; i < 4; i++) {
      int vid = tid + i*256;
      int r = vid >> 3, c8 = (vid & 7) * 8;
      *(bf16x8*)&As[r][c8] = *(const bf16x8*)(A + (size_t)(m0+r)*K + k0 + c8);
    }
#pragma unroll
    for (int i = 0; i < 2; i++) {
      int vid = tid + i*256;
      int r = vid >> 3, c8 = (vid & 7) * 8;
      *(bf16x8*)&Bs[r][c8] = *(const bf16x8*)(Bt + (size_t)(n0+r)*K + k0 + c8);
    }
    __syncthreads();
#pragma unroll
    for (int c = 0; c < 2; c++) {
      bf16x8 af[4], bfr[2];
#pragma unroll
      for (int mt = 0; mt < 4; mt++)
        af[mt] = *(const bf16x8*)&As[wr*64 + mt*16 + ln][c*32 + qd*8];
#pragma unroll
      for (int nt = 0; nt < 2; nt++)
        bfr[nt] = *(const bf16x8*)&Bs[wc*32 + nt*16 + ln][c*32 + qd*8];
#pragma unroll
      for (int mt = 0; mt < 4; mt++)
#pragma unroll
        for (int nt = 0; nt < 2; nt++)
          acc[mt][nt] = __builtin_amdgcn_mfma_f32_16x16x32_bf16(af[mt], bfr[nt], acc[mt][nt], 0, 0, 0);
    }
  }
#pragma unroll
  for (int mt = 0; mt < 4; mt++)
#pragma unroll
    for (int nt = 0; nt < 2; nt++)
#pragma unroll
      for (int r = 0; r < 4; r++) {
        int gm = m0 + wr*64 + mt*16 + qd*4 + r;
        int gn = n0 + wc*32 + nt*16 + ln;
        float v = acc[mt][nt][r];
        if (bias)  v += bias[gn];
        if (resid) v += resid[(size_t)gm*N + gn];
        if (OUT_BF16) sto(v, &((bf16_t*)Cout)[(size_t)gm*N + gn]);
        else          sto(v, &((float*)Cout)[(size_t)gm*N + gn]);
      }
}

// =========================== 3-term bf16 MFMA GEMM (fp32 emulation) ===========================
__global__ __launch_bounds__(256) void gemm3_kernel(
    const bf16_t* __restrict__ Ah, const bf16_t* __restrict__ Al,
    const bf16_t* __restrict__ Bth, const bf16_t* __restrict__ Btl,
    float* __restrict__ C, int M, int N, int K)
{
  __shared__ bf16_t Ash[128][72];
  __shared__ bf16_t Asl[128][72];
  __shared__ bf16_t Bsh[64][72];
  __shared__ bf16_t Bsl[64][72];
  const int tid = threadIdx.x;
  const int m0 = blockIdx.x * 128, n0 = blockIdx.y * 64;
  const int w = tid >> 6, lane = tid & 63;
  const int wr = w >> 1, wc = w & 1;
  const int ln = lane & 15, qd = lane >> 4;
  f32x4 zero = {0.f, 0.f, 0.f, 0.f};
  f32x4 acc[4][2];
#pragma unroll
  for (int a = 0; a < 4; a++)
#pragma unroll
    for (int b = 0; b < 2; b++) acc[a][b] = zero;

  for (int k0 = 0; k0 < K; k0 += 64) {
    __syncthreads();
#pragma unroll
    for (int i = 0; i < 4; i++) {
      int vid = tid + i*256;
      int r = vid >> 3, c8 = (vid & 7) * 8;
      *(bf16x8*)&Ash[r][c8] = *(const bf16x8*)(Ah + (size_t)(m0+r)*K + k0 + c8);
      *(bf16x8*)&Asl[r][c8] = *(const bf16x8*)(Al + (size_t)(m0+r)*K + k0 + c8);
    }
#pragma unroll
    for (int i = 0; i < 2; i++) {
      int vid = tid + i*256;
      int r = vid >> 3, c8 = (vid & 7) * 8;
      *(bf16x8*)&Bsh[r][c8] = *(const bf16x8*)(Bth + (size_t)(n0+r)*K + k0 + c8);
      *(bf16x8*)&Bsl[r][c8] = *(const bf16x8*)(Btl + (size_t)(n0+r)*K + k0 + c8);
    }
    __syncthreads();
#pragma unroll
    for (int c = 0; c < 2; c++) {
      bf16x8 afh[4], afl[4], bfh[2], bfl[2];
#pragma unroll
      for (int mt = 0; mt < 4; mt++) {
        afh[mt] = *(const bf16x8*)&Ash[wr*64 + mt*16 + ln][c*32 + qd*8];
        afl[mt] = *(const bf16x8*)&Asl[wr*64 + mt*16 + ln][c*32 + qd*8];
      }
#pragma unroll
      for (int nt = 0; nt < 2; nt++) {
        bfh[nt] = *(const bf16x8*)&Bsh[wc*32 + nt*16 + ln][c*32 + qd*8];
        bfl[nt] = *(const bf16x8*)&Bsl[wc*32 + nt*16 + ln][c*32 + qd*8];
      }
#pragma unroll
      for (int mt = 0; mt < 4; mt++)
#pragma unroll
        for (int nt = 0; nt < 2; nt++) {
          acc[mt][nt] = __builtin_amdgcn_mfma_f32_16x16x32_bf16(afh[mt], bfl[nt], acc[mt][nt], 0, 0, 0);
          acc[mt][nt] = __builtin_amdgcn_mfma_f32_16x16x32_bf16(afl[mt], bfh[nt], acc[mt][nt], 0, 0, 0);
          acc[mt][nt] = __builtin_amdgcn_mfma_f32_16x16x32_bf16(afh[mt], bfh[nt], acc[mt][nt], 0, 0, 0);
        }
    }
  }
#pragma unroll
  for (int mt = 0; mt < 4; mt++)
#pragma unroll
    for (int nt = 0; nt < 2; nt++)
#pragma unroll
      for (int r = 0; r < 4; r++) {
        int gm = m0 + wr*64 + mt*16 + qd*4 + r;
        int gn = n0 + wc*32 + nt*16 + ln;
        C[(size_t)gm*N + gn] = acc[mt][nt][r];
      }
}

// =========================== GEGLU ===========================
__global__ __launch_bounds__(256) void geglu_kernel(
    const bf16_t* __restrict__ proj, bf16_t* __restrict__ gg)
{
  int idx = blockIdx.x * 256 + threadIdx.x;
  int m = idx / 320, c4 = (idx - m*320) * 4;
  bf16x4 a = *(const bf16x4*)(proj + (size_t)m*2560 + c4);
  bf16x4 g = *(const bf16x4*)(proj + (size_t)m*2560 + 1280 + c4);
  bf16x4 r;
#pragma unroll
  for (int i = 0; i < 4; i++) {
    float gf = b2f(g[i]);
    float ge = 0.5f * gf * (1.f + erff(gf * 0.70710678118654752f));
    r[i] = f2b(b2f(a[i]) * ge);
  }
  *(bf16x4*)(gg + (size_t)m*1280 + c4) = r;
}

// =========================== launch ===========================
extern "C" void kernel_launch(void* const* d_in, const int* in_sizes, int n_in,
                              void* d_out, int out_size, void* d_ws, size_t ws_size,
                              hipStream_t stream)
{
  const float* x    = (const float*)d_in[0];
  const float* ctx  = (const float*)d_in[1];
  const float* fam  = (const float*)d_in[2];
  const float* g1   = (const float*)d_in[3];
  const float* b1   = (const float*)d_in[4];
  const float* g2   = (const float*)d_in[5];
  const float* b2   = (const float*)d_in[6];
  const float* g3   = (const float*)d_in[7];
  const float* b3   = (const float*)d_in[8];
  const float* Wq1  = (const float*)d_in[9];
  const float* Wk1  = (const float*)d_in[10];
  const float* Wv1  = (const float*)d_in[11];
  const float* Wo1  = (const float*)d_in[12];
  const float* bo1  = (const float*)d_in[13];
  const float* Wq2  = (const float*)d_in[14];
  const float* Wk2  = (const float*)d_in[15];
  const float* Wv2  = (const float*)d_in[16];
  const float* Wo2  = (const float*)d_in[17];
  const float* bo2  = (const float*)d_in[18];
  const float* Wff1 = (const float*)d_in[19];
  const float* bff1 = (const float*)d_in[20];
  const float* Wff2 = (const float*)d_in[21];
  const float* bff2 = (const float*)d_in[22];
  const int*   ufca = (const int*)d_in[23];

  char* ws = (char*)d_ws;
  bf16_t* qkvb = (bf16_t*)(ws + 0);          //  7,864,320  bf16 [4096][960]
  bf16_t* vtg  = (bf16_t*)(ws + 7864320);    //  2,621,440  bf16 [8][40][4096]
  bf16_t* o1a  = (bf16_t*)(ws + 10485760);   //  2,621,440  bf16 [4096][320]
  bf16_t* h1b  = (bf16_t*)(ws + 13107200);   //  2,621,440  bf16 [4096][320]
  bf16_t* h2hi = (bf16_t*)(ws + 15728640);   //  2,621,440  bf16 [4096][320]
  bf16_t* h2lo = (bf16_t*)(ws + 18350080);   //  2,621,440  bf16 [4096][320]
  float*  x2   = (float*)(ws + 20971520);    //  5,242,880  f32  [4096][320]
  float*  q2   = (float*)(ws + 26214400);    //  5,242,880  f32  [4096][320]
  float*  kv2  = (float*)(ws + 31457280);    //    197,120  f32  [77][640]
  bf16_t* o2   = (bf16_t*)(ws + 31654400);   //  2,621,440  bf16 [4096][320]
  float*  x3   = (float*)(ws + 34275840);    //  5,242,880  f32  [4096][320]
  bf16_t* h3b  = (bf16_t*)(ws + 39518720);   //  2,621,440  bf16 [4096][320]
  bf16_t* wqkvt = (bf16_t*)(ws + 42140160);  //    614,400
  bf16_t* wo1t  = (bf16_t*)(ws + 42754560);  //    204,800
  float*  wkv2t = (float*)(ws + 42959360);   //  1,966,080  f32 [640][768]
  bf16_t* wo2t  = (bf16_t*)(ws + 44925440);  //    204,800
  bf16_t* wff1t = (bf16_t*)(ws + 45130240);  //  1,638,400
  bf16_t* wff2t = (bf16_t*)(ws + 46768640);  //    819,200
  float*  lpart = (float*)(ws + 47587840);   //    262,144  f32 [2][8][4096]
  bf16_t* wq2th = (bf16_t*)(ws + 47849984);  //    204,800
  bf16_t* wq2tl = (bf16_t*)(ws + 48054784);  //    204,800
  bf16_t* famh  = (bf16_t*)(ws + 48259584);  //     18,432  bf16 [96][96]
  bf16_t* faml  = (bf16_t*)(ws + 48278016);  //     18,432
  bf16_t* k2h   = (bf16_t*)(ws + 48296448);  //     98,304  bf16 [8][96][64]
  bf16_t* k2l   = (bf16_t*)(ws + 48394752);  //     98,304
  bf16_t* v2t   = (bf16_t*)(ws + 48493056);  //     73,728  bf16 [8][48][96]  -> end 48,566,784
  // opart overlaps x2..~h3b (dead during flash+merge): f32 [2][8][4096][40]
  float*  opart = (float*)(ws + 20971520);
  bf16_t* proj = (bf16_t*)(ws + 0);          // bf16 [4096][2560] (FF phase only)
  bf16_t* gg   = (bf16_t*)(ws + 20971520);   // bf16 [4096][1280] (FF phase only)

  float* xout = (float*)d_out;

  prep_kernel<<<1024, 256, 0, stream>>>(Wq1, Wk1, Wv1, Wo1, Wq2, Wk2, Wv2, Wo2, Wff1, Wff2, fam,
                                        wqkvt, wo1t, wkv2t, wo2t, wff1t, wff2t, wq2th, wq2tl,
                                        famh, faml);
  // --- attn1 (bf16 MFMA flash) ---
  ln_kernel<bf16_t><<<1024, 256, 0, stream>>>(x, g1, b1, h1b);
  gemm_bf16_kernel<1><<<dim3(32,15), 256, 0, stream>>>(h1b, wqkvt, nullptr, nullptr, qkvb, 4096, 960, 320);
  repack_vt_kernel<<<dim3(64,8), 256, 0, stream>>>(qkvb, vtg);
  flash_self_kernel<<<dim3(64,8,2), 256, 0, stream>>>(qkvb, vtg, opart, lpart);
  merge_o1_kernel<<<5120, 256, 0, stream>>>(opart, lpart, o1a);
  gemm_bf16_kernel<0><<<dim3(32,5), 256, 0, stream>>>(o1a, wo1t, bo1, x, x2, 4096, 320, 320);
  // --- attn2 (sim2 path: fp32-emulated MFMA throughout) ---
  ln2_split_kernel<<<1024, 256, 0, stream>>>(x2, g2, b2, h2hi, h2lo);
  gemm3_kernel<<<dim3(32,5), 256, 0, stream>>>(h2hi, h2lo, wq2th, wq2tl, q2, 4096, 320, 320);
  kv2_dot_kernel<<<3080, 256, 0, stream>>>(ctx, wkv2t, kv2);
  kv2_post_kernel<<<336, 256, 0, stream>>>(kv2, k2h, k2l, v2t);
  attn_cross_kernel<<<dim3(64,8), 256, 0, stream>>>(q2, k2h, k2l, famh, faml, v2t, ufca, o2);
  gemm_bf16_kernel<0><<<dim3(32,5), 256, 0, stream>>>(o2, wo2t, bo2, x2, x3, 4096, 320, 320);
  // --- GEGLU FF ---
  ln_kernel<bf16_t><<<1024, 256, 0, stream>>>(x3, g3, b3, h3b);
  gemm_bf16_kernel<1><<<dim3(32,40), 256, 0, stream>>>(h3b, wff1t, bff1, nullptr, proj, 4096, 2560, 320);
  geglu_kernel<<<5120, 256, 0, stream>>>(proj, gg);
  gemm_bf16_kernel<0><<<dim3(32,5), 256, 0, stream>>>(gg, wff2t, bff2, x3, xout, 4096, 320, 1280);
}